// Round 1
// baseline (488.280 us; speedup 1.0000x reference)
//
#include <hip/hip_runtime.h>
#include <cstdint>
#include <cstddef>

typedef unsigned short US;
typedef __bf16 bf16_t;
typedef bf16_t bf16x8 __attribute__((ext_vector_type(8)));
typedef float  f32x4  __attribute__((ext_vector_type(4)));
typedef US     us8    __attribute__((ext_vector_type(8)));
typedef US     us4    __attribute__((ext_vector_type(4)));

#define AS1 __attribute__((address_space(1)))
#define AS3 __attribute__((address_space(3)))

// async global->LDS, 16B per lane; LDS dest must be wave-uniform base (+lane*16)
__device__ __forceinline__ void gl_lds16(const void* g, void* l) {
    __builtin_amdgcn_global_load_lds((AS1 unsigned int*)(size_t)g,
                                     (AS3 unsigned int*)l, 16, 0, 0);
}

__device__ __forceinline__ US f2bf(float f) {
    unsigned u = __builtin_bit_cast(unsigned, f);
    u += 0x7FFFu + ((u >> 16) & 1u);   // RNE (inputs are finite)
    return (US)(u >> 16);
}

__device__ __forceinline__ bf16x8 ldv8(const US* p) {
    return __builtin_bit_cast(bf16x8, *(const us8*)p);
}

// ---------------- elementwise converts ----------------
__global__ void conv_bf16(const float* __restrict__ in, US* __restrict__ out, int n4) {
    int i = blockIdx.x * blockDim.x + threadIdx.x;
    if (i < n4) {
        float4 f = ((const float4*)in)[i];
        us4 o = { f2bf(f.x), f2bf(f.y), f2bf(f.z), f2bf(f.w) };
        ((us4*)out)[i] = o;
    }
}

__global__ void conv_mask(const int* __restrict__ in, US* __restrict__ out, int n4) {
    int i = blockIdx.x * blockDim.x + threadIdx.x;
    if (i < n4) {
        int4 m = ((const int4*)in)[i];
        us4 o = { (US)(m.x ? 1 : 0), (US)(m.y ? 1 : 0),
                  (US)(m.z ? 1 : 0), (US)(m.w ? 1 : 0) };
        ((us4*)out)[i] = o;
    }
}

// ---------------- weight transpose+convert: W[k][n] f32 -> WT[n][k] bf16 ----------------
__global__ void wt_conv(const float* __restrict__ Wq, const float* __restrict__ Wk,
                        const float* __restrict__ Wv, const float* __restrict__ Wo,
                        US* __restrict__ outbase) {
    const float* W = (blockIdx.z == 0) ? Wq : (blockIdx.z == 1) ? Wk
                   : (blockIdx.z == 2) ? Wv : Wo;
    US* WT = outbase + (size_t)blockIdx.z * 1024 * 1024;
    __shared__ float t[32][33];
    int tx = threadIdx.x & 31, ty = threadIdx.x >> 5;
    int x = blockIdx.x * 32 + tx;
#pragma unroll
    for (int r = 0; r < 4; ++r)
        t[ty + r * 8][tx] = W[(size_t)(blockIdx.y * 32 + ty + r * 8) * 1024 + x];
    __syncthreads();
    int nx = blockIdx.y * 32 + tx;
#pragma unroll
    for (int r = 0; r < 4; ++r)
        WT[(size_t)(blockIdx.x * 32 + ty + r * 8) * 1024 + nx] = f2bf(t[tx][ty + r * 8]);
}

// ---------------- V transpose: [bh][4096][128] -> [bh][128][4096] (bf16) ----------------
__global__ void v_transpose(const US* __restrict__ Vh, US* __restrict__ VTh) {
    __shared__ US t[32][33];
    int tx = threadIdx.x & 31, ty = threadIdx.x >> 5;
    size_t base = (size_t)blockIdx.z * 4096 * 128;
    int t0 = blockIdx.x * 32, d0 = blockIdx.y * 32;
#pragma unroll
    for (int r = 0; r < 4; ++r)
        t[ty + r * 8][tx] = Vh[base + (size_t)(t0 + ty + r * 8) * 128 + d0 + tx];
    __syncthreads();
#pragma unroll
    for (int r = 0; r < 4; ++r)
        VTh[base + (size_t)(d0 + ty + r * 8) * 4096 + t0 + tx] = t[tx][ty + r * 8];
}

// ---------------- GEMM: C[M,1024] = A[M,1024]bf16 @ Bt[1024,1024]^T + bias ----------------
// MODE 0: bf16 split-heads out [b,h,T,128], row=b*T+t, col=h*128+d, scale applied
// MODE 1: fp32 row-major out [M,1024]
template <int MODE>
__global__ __launch_bounds__(256, 2)
void gemm_bt(const US* __restrict__ A, const US* __restrict__ Bt,
             const float* __restrict__ bias, void* __restrict__ out,
             int tlog2, float scale) {
    constexpr int K = 1024, N = 1024, BK = 64;
    __shared__ US As[128 * BK];
    __shared__ US Bs[128 * BK];
    const int tid = threadIdx.x;
    const int wv = tid >> 6, ln = tid & 63;
    const int g = ln >> 4, c15 = ln & 15;
    const int m0 = blockIdx.x * 128, n0 = blockIdx.y * 128;
    const int wm = (wv & 1) * 64, wn = (wv >> 1) * 64;

    f32x4 acc[4][4];
    const f32x4 z = {0.f, 0.f, 0.f, 0.f};
#pragma unroll
    for (int i = 0; i < 4; ++i)
#pragma unroll
        for (int j = 0; j < 4; ++j) acc[i][j] = z;

    const US* Ab = A + (size_t)m0 * K;
    const US* Bb = Bt + (size_t)n0 * K;

    for (int k0 = 0; k0 < K; k0 += BK) {
        __syncthreads();
#pragma unroll
        for (int q = 0; q < 4; ++q) {
            int eb = (q * 256 + wv * 64) * 8;
            int e = eb + ln * 8;
            int r = e >> 6, c = e & 63;
            gl_lds16(Ab + (size_t)r * K + k0 + c, &As[eb]);
            gl_lds16(Bb + (size_t)r * K + k0 + c, &Bs[eb]);
        }
        __syncthreads();
#pragma unroll
        for (int kk = 0; kk < BK; kk += 32) {
            int ak = kk + g * 8;
            bf16x8 a[4], b[4];
#pragma unroll
            for (int i = 0; i < 4; ++i) a[i] = ldv8(&As[(wm + i * 16 + c15) * BK + ak]);
#pragma unroll
            for (int j = 0; j < 4; ++j) b[j] = ldv8(&Bs[(wn + j * 16 + c15) * BK + ak]);
#pragma unroll
            for (int i = 0; i < 4; ++i)
#pragma unroll
                for (int j = 0; j < 4; ++j)
                    acc[i][j] = __builtin_amdgcn_mfma_f32_16x16x32_bf16(a[i], b[j], acc[i][j], 0, 0, 0);
        }
    }

#pragma unroll
    for (int i = 0; i < 4; ++i) {
#pragma unroll
        for (int j = 0; j < 4; ++j) {
            int col = n0 + wn + j * 16 + c15;
            float bvv = bias[col];
#pragma unroll
            for (int r = 0; r < 4; ++r) {
                int row = m0 + wm + i * 16 + g * 4 + r;
                float v = (acc[i][j][r] + bvv) * scale;
                if (MODE == 0) {
                    int b_ = row >> tlog2;
                    int t = row & ((1 << tlog2) - 1);
                    int h = col >> 7, d = col & 127;
                    ((US*)out)[(((size_t)(b_ * 8 + h) << tlog2) + t) * 128 + d] = f2bf(v);
                } else {
                    ((float*)out)[(size_t)row * N + col] = v;
                }
            }
        }
    }
}

// ---------------- flash attention ----------------
// grid: x = 8 (q-tiles of 64), y = 32 (b*8+h). block = 256 (4 waves, 16 q-rows each)
// no-running-max softmax: scores bounded (|s| < ~3), p = exp(s)*mask01, out = O/l
__global__ __launch_bounds__(256)
void flash(const US* __restrict__ Qh, const US* __restrict__ Kh,
           const US* __restrict__ VTh, const US* __restrict__ Mk,
           US* __restrict__ AO) {
    __shared__ US Qs[64 * 128];       // [q][d]       16KB
    __shared__ US Ks[64 * 128];       // [kv][d]      16KB
    __shared__ US Vs[128 * 64];       // [d][kv]      16KB
    __shared__ US Ps[4][16 * 64];     // per-wave P   8KB
    const int tid = threadIdx.x, wv = tid >> 6, ln = tid & 63;
    const int g = ln >> 4, c15 = ln & 15;
    const int q0 = blockIdx.x * 64;
    const int bh = blockIdx.y;
    const int b_ = bh >> 3, h = bh & 7;
    const int wq = wv * 16;

    // stage Q tile (contiguous 16KB)
    {
        const US* Qb = Qh + ((size_t)bh * 512 + q0) * 128;
#pragma unroll
        for (int q = 0; q < 4; ++q) {
            int eb = (q * 256 + wv * 64) * 8;
            gl_lds16(Qb + eb + ln * 8, &Qs[eb]);
        }
    }
    __syncthreads();
    bf16x8 qa[4];
#pragma unroll
    for (int s = 0; s < 4; ++s) qa[s] = ldv8(&Qs[(wq + c15) * 128 + s * 32 + g * 8]);

    f32x4 o[8];
    const f32x4 z = {0.f, 0.f, 0.f, 0.f};
#pragma unroll
    for (int j = 0; j < 8; ++j) o[j] = z;
    float l4[4] = {0.f, 0.f, 0.f, 0.f};

    const US* mrow = Mk + (size_t)(b_ * 512 + q0 + wq + g * 4) * 4096 + c15;
    const US* Kbase = Kh + (size_t)bh * 4096 * 128;
    const US* Vbase = VTh + (size_t)bh * 128 * 4096;
    US* Pw = &Ps[wv][0];

    for (int kv0 = 0; kv0 < 4096; kv0 += 64) {
        __syncthreads();
        // stage K tile [64 kv][128 d] (contiguous) and V^T tile [128 d][64 kv]
        const US* Kb = Kbase + (size_t)kv0 * 128;
#pragma unroll
        for (int q = 0; q < 4; ++q) {
            int eb = (q * 256 + wv * 64) * 8;
            gl_lds16(Kb + eb + ln * 8, &Ks[eb]);
        }
#pragma unroll
        for (int q = 0; q < 4; ++q) {
            int eb = (q * 256 + wv * 64) * 8;
            int e = eb + ln * 8;
            int d = e >> 6, c = e & 63;
            gl_lds16(Vbase + (size_t)d * 4096 + kv0 + c, &Vs[eb]);
        }
        // mask values for this tile (global scalar loads, hidden under staging)
        US mv[4][4];
#pragma unroll
        for (int r = 0; r < 4; ++r) {
            const US* pr = mrow + (size_t)r * 4096 + kv0;
#pragma unroll
            for (int j = 0; j < 4; ++j) mv[r][j] = pr[j * 16];
        }
        __syncthreads();

        // S = Q K^T  (16 q-rows x 64 kv per wave)
        f32x4 s[4];
#pragma unroll
        for (int j = 0; j < 4; ++j) s[j] = z;
#pragma unroll
        for (int ks = 0; ks < 4; ++ks) {
#pragma unroll
            for (int j = 0; j < 4; ++j) {
                bf16x8 kb = ldv8(&Ks[(j * 16 + c15) * 128 + ks * 32 + g * 8]);
                s[j] = __builtin_amdgcn_mfma_f32_16x16x32_bf16(qa[ks], kb, s[j], 0, 0, 0);
            }
        }
        // p = exp(s) * mask; accumulate l; write P to per-wave LDS in A-layout order
#pragma unroll
        for (int j = 0; j < 4; ++j) {
#pragma unroll
            for (int r = 0; r < 4; ++r) {
                float pp = __expf(s[j][r]);
                pp = mv[r][j] ? pp : 0.0f;
                l4[r] += pp;
                Pw[(g * 4 + r) * 64 + c15 + j * 16] = f2bf(pp);
            }
        }
        // O += P V
#pragma unroll
        for (int ks = 0; ks < 2; ++ks) {
            bf16x8 pa = ldv8(&Pw[c15 * 64 + ks * 32 + g * 8]);
#pragma unroll
            for (int j = 0; j < 8; ++j) {
                bf16x8 vb = ldv8(&Vs[(j * 16 + c15) * 64 + ks * 32 + g * 8]);
                o[j] = __builtin_amdgcn_mfma_f32_16x16x32_bf16(pa, vb, o[j], 0, 0, 0);
            }
        }
    }

    // reduce l across the 16 lanes sharing g, normalize, store (wipe rows -> 0)
    float inv[4];
#pragma unroll
    for (int r = 0; r < 4; ++r) {
        float l = l4[r];
        l += __shfl_xor(l, 1); l += __shfl_xor(l, 2);
        l += __shfl_xor(l, 4); l += __shfl_xor(l, 8);
        inv[r] = (l > 0.f) ? 1.0f / l : 0.0f;
    }
    US* Ob = AO + (size_t)(b_ * 512 + q0 + wq + g * 4) * 1024 + h * 128 + c15;
#pragma unroll
    for (int j = 0; j < 8; ++j)
#pragma unroll
        for (int r = 0; r < 4; ++r)
            Ob[(size_t)r * 1024 + j * 16] = f2bf(o[j][r] * inv[r]);
}

// ---------------- launch ----------------
extern "C" void kernel_launch(void* const* d_in, const int* in_sizes, int n_in,
                              void* d_out, int out_size, void* d_ws, size_t ws_size,
                              hipStream_t stream) {
    (void)in_sizes; (void)n_in; (void)out_size; (void)ws_size;
    const float* Xq  = (const float*)d_in[0];
    const float* Xkv = (const float*)d_in[1];
    const int*   Mi  = (const int*)d_in[2];
    const float* Wq  = (const float*)d_in[3];
    const float* bq  = (const float*)d_in[4];
    const float* Wk  = (const float*)d_in[5];
    const float* bk  = (const float*)d_in[6];
    const float* Wv  = (const float*)d_in[7];
    const float* bv  = (const float*)d_in[8];
    const float* Wo  = (const float*)d_in[9];
    const float* bo  = (const float*)d_in[10];
    float* out = (float*)d_out;

    char* p = (char*)d_ws;
    US* XqB  = (US*)p; p += (size_t)2048 * 1024 * 2;
    US* XkvB = (US*)p; p += (size_t)16384 * 1024 * 2;
    US* WT   = (US*)p; p += (size_t)4 * 1024 * 1024 * 2;
    US* MB   = (US*)p; p += (size_t)4 * 512 * 4096 * 2;
    US* Qh   = (US*)p; p += (size_t)2048 * 1024 * 2;
    US* Kh   = (US*)p; p += (size_t)16384 * 1024 * 2;
    US* Vh   = (US*)p; p += (size_t)16384 * 1024 * 2;
    US* VTh  = (US*)p; p += (size_t)16384 * 1024 * 2;
    US* AO   = (US*)p; p += (size_t)2048 * 1024 * 2;

    conv_bf16<<<2048, 256, 0, stream>>>(Xq, XqB, 2048 * 1024 / 4);
    conv_bf16<<<16384, 256, 0, stream>>>(Xkv, XkvB, 16384 * 1024 / 4);
    conv_mask<<<8192, 256, 0, stream>>>(Mi, MB, 4 * 512 * 4096 / 4);
    wt_conv<<<dim3(32, 32, 4), 256, 0, stream>>>(Wq, Wk, Wv, Wo, WT);

    // Q projection: fold softmax scale 1/sqrt(128) into Q (and its bias)
    gemm_bt<0><<<dim3(16, 8), 256, 0, stream>>>(XqB, WT, bq, Qh, 9, 0.08838834764831843f);
    gemm_bt<0><<<dim3(128, 8), 256, 0, stream>>>(XkvB, WT + 1048576, bk, Kh, 12, 1.0f);
    gemm_bt<0><<<dim3(128, 8), 256, 0, stream>>>(XkvB, WT + 2097152, bv, Vh, 12, 1.0f);
    v_transpose<<<dim3(128, 4, 32), 256, 0, stream>>>(Vh, VTh);
    flash<<<dim3(8, 32), 256, 0, stream>>>(Qh, Kh, VTh, MB, AO);
    gemm_bt<1><<<dim3(16, 8), 256, 0, stream>>>(AO, WT + 3145728, bo, out, 0, 1.0f);
}

// Round 2
// 382.271 us; speedup vs baseline: 1.2773x; 1.2773x over previous
//
#include <hip/hip_runtime.h>
#include <cstdint>
#include <cstddef>

typedef unsigned short US;
typedef __bf16 bf16_t;
typedef bf16_t bf16x8 __attribute__((ext_vector_type(8)));
typedef float  f32x4  __attribute__((ext_vector_type(4)));
typedef US     us8    __attribute__((ext_vector_type(8)));
typedef US     us4    __attribute__((ext_vector_type(4)));

#define AS1 __attribute__((address_space(1)))
#define AS3 __attribute__((address_space(3)))

// async global->LDS, 16B per lane; LDS dest is wave-uniform base + lane*16
__device__ __forceinline__ void gl_lds16(const void* g, void* l) {
    __builtin_amdgcn_global_load_lds((AS1 unsigned int*)(size_t)g,
                                     (AS3 unsigned int*)l, 16, 0, 0);
}

__device__ __forceinline__ US f2bf(float f) {
    unsigned u = __builtin_bit_cast(unsigned, f);
    u += 0x7FFFu + ((u >> 16) & 1u);   // RNE (inputs finite)
    return (US)(u >> 16);
}

__device__ __forceinline__ bf16x8 ldv8(const US* p) {
    return __builtin_bit_cast(bf16x8, *(const us8*)p);
}

// ---------------- elementwise converts ----------------
__global__ void conv_bf16(const float* __restrict__ in, US* __restrict__ out, int n4) {
    int i = blockIdx.x * blockDim.x + threadIdx.x;
    if (i < n4) {
        float4 f = ((const float4*)in)[i];
        us4 o = { f2bf(f.x), f2bf(f.y), f2bf(f.z), f2bf(f.w) };
        ((us4*)out)[i] = o;
    }
}

__global__ void conv_mask(const int* __restrict__ in, US* __restrict__ out, int n4) {
    int i = blockIdx.x * blockDim.x + threadIdx.x;
    if (i < n4) {
        int4 m = ((const int4*)in)[i];
        us4 o = { (US)(m.x ? 1 : 0), (US)(m.y ? 1 : 0),
                  (US)(m.z ? 1 : 0), (US)(m.w ? 1 : 0) };
        ((us4*)out)[i] = o;
    }
}

// ---------------- weight transpose+convert: W[k][n] f32 -> WT[n][k] bf16 ----------------
__global__ void wt_conv(const float* __restrict__ Wq, const float* __restrict__ Wk,
                        const float* __restrict__ Wv, const float* __restrict__ Wo,
                        US* __restrict__ outbase) {
    const float* W = (blockIdx.z == 0) ? Wq : (blockIdx.z == 1) ? Wk
                   : (blockIdx.z == 2) ? Wv : Wo;
    US* WT = outbase + (size_t)blockIdx.z * 1024 * 1024;
    __shared__ float t[32][33];
    int tx = threadIdx.x & 31, ty = threadIdx.x >> 5;
    int x = blockIdx.x * 32 + tx;
#pragma unroll
    for (int r = 0; r < 4; ++r)
        t[ty + r * 8][tx] = W[(size_t)(blockIdx.y * 32 + ty + r * 8) * 1024 + x];
    __syncthreads();
    int nx = blockIdx.y * 32 + tx;
#pragma unroll
    for (int r = 0; r < 4; ++r)
        WT[(size_t)(blockIdx.x * 32 + ty + r * 8) * 1024 + nx] = f2bf(t[tx][ty + r * 8]);
}

// ---------------- V transpose: [bh][4096][128] -> [bh][128][4096] (bf16) ----------------
__global__ void v_transpose(const US* __restrict__ Vh, US* __restrict__ VTh) {
    __shared__ US t[32][33];
    int tx = threadIdx.x & 31, ty = threadIdx.x >> 5;
    size_t base = (size_t)blockIdx.z * 4096 * 128;
    int t0 = blockIdx.x * 32, d0 = blockIdx.y * 32;
#pragma unroll
    for (int r = 0; r < 4; ++r)
        t[ty + r * 8][tx] = Vh[base + (size_t)(t0 + ty + r * 8) * 128 + d0 + tx];
    __syncthreads();
#pragma unroll
    for (int r = 0; r < 4; ++r)
        VTh[base + (size_t)(d0 + ty + r * 8) * 4096 + t0 + tx] = t[tx][ty + r * 8];
}

// ---------------- GEMM: C[M,1024] = A[M,1024]bf16 @ Bt[1024,1024]^T + bias ----------------
// LDS rows (BK=64 el) are chunk-XOR swizzled: chunk c of row r lives at c^(r&7).
// MODE 0: bf16 split-heads out [b,h,T,128]; MODE 1: fp32 row-major [M,1024]
template <int MODE>
__global__ __launch_bounds__(256, 2)
void gemm_bt(const US* __restrict__ A, const US* __restrict__ Bt,
             const float* __restrict__ bias, void* __restrict__ out,
             int tlog2, float scale) {
    constexpr int K = 1024, N = 1024, BK = 64;
    __shared__ US As[128 * BK];
    __shared__ US Bs[128 * BK];
    const int tid = threadIdx.x;
    const int wv = tid >> 6, ln = tid & 63;
    const int g = ln >> 4, c15 = ln & 15;
    const int m0 = blockIdx.x * 128, n0 = blockIdx.y * 128;
    const int wm = (wv & 1) * 64, wn = (wv >> 1) * 64;

    f32x4 acc[4][4];
    const f32x4 z = {0.f, 0.f, 0.f, 0.f};
#pragma unroll
    for (int i = 0; i < 4; ++i)
#pragma unroll
        for (int j = 0; j < 4; ++j) acc[i][j] = z;

    const US* Ab = A + (size_t)m0 * K;
    const US* Bb = Bt + (size_t)n0 * K;

    for (int k0 = 0; k0 < K; k0 += BK) {
        __syncthreads();
#pragma unroll
        for (int q = 0; q < 4; ++q) {
            int eb = (q * 256 + wv * 64) * 8;
            int r = (eb >> 6) + (ln >> 3);          // 8 rows per instr
            int sw = (ln & 7) ^ (r & 7);
            gl_lds16(Ab + (size_t)r * K + k0 + sw * 8, &As[eb]);
            gl_lds16(Bb + (size_t)r * K + k0 + sw * 8, &Bs[eb]);
        }
        __syncthreads();
#pragma unroll
        for (int ks = 0; ks < 2; ++ks) {
            bf16x8 a[4], b[4];
#pragma unroll
            for (int i = 0; i < 4; ++i) {
                int p = (ks * 4 + g) ^ (c15 & 7);
                a[i] = ldv8(&As[(wm + i * 16 + c15) * BK + p * 8]);
            }
#pragma unroll
            for (int j = 0; j < 4; ++j) {
                int p = (ks * 4 + g) ^ (c15 & 7);
                b[j] = ldv8(&Bs[(wn + j * 16 + c15) * BK + p * 8]);
            }
#pragma unroll
            for (int i = 0; i < 4; ++i)
#pragma unroll
                for (int j = 0; j < 4; ++j)
                    acc[i][j] = __builtin_amdgcn_mfma_f32_16x16x32_bf16(a[i], b[j], acc[i][j], 0, 0, 0);
        }
    }

#pragma unroll
    for (int i = 0; i < 4; ++i) {
#pragma unroll
        for (int j = 0; j < 4; ++j) {
            int col = n0 + wn + j * 16 + c15;
            float bvv = bias[col];
#pragma unroll
            for (int r = 0; r < 4; ++r) {
                int row = m0 + wm + i * 16 + g * 4 + r;
                float v = (acc[i][j][r] + bvv) * scale;
                if (MODE == 0) {
                    int b_ = row >> tlog2;
                    int t = row & ((1 << tlog2) - 1);
                    int h = col >> 7, d = col & 127;
                    ((US*)out)[(((size_t)(b_ * 8 + h) << tlog2) + t) * 128 + d] = f2bf(v);
                } else {
                    ((float*)out)[(size_t)row * N + col] = v;
                }
            }
        }
    }
}

// ---------------- fused K+V projection GEMM (shared A staging) ----------------
__global__ __launch_bounds__(256, 2)
void gemm_kv(const US* __restrict__ A, const US* __restrict__ BtK,
             const US* __restrict__ BtV, const float* __restrict__ bk,
             const float* __restrict__ bv, US* __restrict__ Kout,
             US* __restrict__ Vout) {
    constexpr int K = 1024, BK = 64;
    __shared__ US As[128 * BK];
    __shared__ US BsK[128 * BK];
    __shared__ US BsV[128 * BK];
    const int tid = threadIdx.x;
    const int wv = tid >> 6, ln = tid & 63;
    const int g = ln >> 4, c15 = ln & 15;
    const int m0 = blockIdx.x * 128, n0 = blockIdx.y * 128;
    const int wm = (wv & 1) * 64, wn = (wv >> 1) * 64;

    f32x4 aK[4][4], aV[4][4];
    const f32x4 z = {0.f, 0.f, 0.f, 0.f};
#pragma unroll
    for (int i = 0; i < 4; ++i)
#pragma unroll
        for (int j = 0; j < 4; ++j) { aK[i][j] = z; aV[i][j] = z; }

    const US* Ab  = A   + (size_t)m0 * K;
    const US* BbK = BtK + (size_t)n0 * K;
    const US* BbV = BtV + (size_t)n0 * K;

    for (int k0 = 0; k0 < K; k0 += BK) {
        __syncthreads();
#pragma unroll
        for (int q = 0; q < 4; ++q) {
            int eb = (q * 256 + wv * 64) * 8;
            int r = (eb >> 6) + (ln >> 3);
            int sw = (ln & 7) ^ (r & 7);
            gl_lds16(Ab  + (size_t)r * K + k0 + sw * 8, &As[eb]);
            gl_lds16(BbK + (size_t)r * K + k0 + sw * 8, &BsK[eb]);
            gl_lds16(BbV + (size_t)r * K + k0 + sw * 8, &BsV[eb]);
        }
        __syncthreads();
#pragma unroll
        for (int ks = 0; ks < 2; ++ks) {
            bf16x8 a[4], bK[4], bV[4];
#pragma unroll
            for (int i = 0; i < 4; ++i) {
                int p = (ks * 4 + g) ^ (c15 & 7);
                a[i] = ldv8(&As[(wm + i * 16 + c15) * BK + p * 8]);
            }
#pragma unroll
            for (int j = 0; j < 4; ++j) {
                int p = (ks * 4 + g) ^ (c15 & 7);
                bK[j] = ldv8(&BsK[(wn + j * 16 + c15) * BK + p * 8]);
                bV[j] = ldv8(&BsV[(wn + j * 16 + c15) * BK + p * 8]);
            }
#pragma unroll
            for (int i = 0; i < 4; ++i)
#pragma unroll
                for (int j = 0; j < 4; ++j) {
                    aK[i][j] = __builtin_amdgcn_mfma_f32_16x16x32_bf16(a[i], bK[j], aK[i][j], 0, 0, 0);
                    aV[i][j] = __builtin_amdgcn_mfma_f32_16x16x32_bf16(a[i], bV[j], aV[i][j], 0, 0, 0);
                }
        }
    }

#pragma unroll
    for (int i = 0; i < 4; ++i) {
#pragma unroll
        for (int j = 0; j < 4; ++j) {
            int col = n0 + wn + j * 16 + c15;
            float bkv = bk[col], bvv = bv[col];
            int h = col >> 7, d = col & 127;
#pragma unroll
            for (int r = 0; r < 4; ++r) {
                int row = m0 + wm + i * 16 + g * 4 + r;
                int b_ = row >> 12, t = row & 4095;
                size_t oi = (((size_t)(b_ * 8 + h) << 12) + t) * 128 + d;
                Kout[oi] = f2bf(aK[i][j][r] + bkv);
                Vout[oi] = f2bf(aV[i][j][r] + bvv);
            }
        }
    }
}

// ---------------- flash attention, split-KV ----------------
// grid: x = 8 q-tiles(64), y = 32 bh, z = 4 kv-splits(1024 each). 256 thr (4 waves).
// no-running-max softmax (scores bounded): partial (O,l) -> combine kernel.
// LDS tiles chunk-XOR swizzled to kill the 16-way ds_read_b128 conflicts.
__global__ __launch_bounds__(256, 3)
void flash(const US* __restrict__ Qh, const US* __restrict__ Kh,
           const US* __restrict__ VTh, const US* __restrict__ Mk,
           float* __restrict__ Opart, float* __restrict__ Lpart) {
    __shared__ US Ks[64 * 128];       // [kv][d]   16KB, swz &15
    __shared__ US Vs[128 * 64];       // [d][kv]   16KB, swz &7
    __shared__ US Qs[64 * 128];       // Q staging; reused as per-wave P after frag load
    const int tid = threadIdx.x, wv = tid >> 6, ln = tid & 63;
    const int g = ln >> 4, c15 = ln & 15;
    const int qt = blockIdx.x, q0 = qt * 64;
    const int bh = blockIdx.y, b_ = bh >> 3;
    const int sp = blockIdx.z, kvbase = sp * 1024;
    const int wq = wv * 16;

    // stage Q tile (swizzled)
    {
        const US* Qb = Qh + ((size_t)bh * 512 + q0) * 128;
#pragma unroll
        for (int q = 0; q < 4; ++q) {
            int eb = (q * 256 + wv * 64) * 8;
            int r = (eb >> 7) + (ln >> 4);      // 4 rows per instr
            int sw = (ln & 15) ^ (r & 15);
            gl_lds16(Qb + (size_t)r * 128 + sw * 8, &Qs[eb]);
        }
    }
    __syncthreads();
    bf16x8 qa[4];
#pragma unroll
    for (int s = 0; s < 4; ++s) {
        int p = (s * 4 + g) ^ c15;              // (wq+c15)&15 == c15
        qa[s] = ldv8(&Qs[(wq + c15) * 128 + p * 8]);
    }
    __syncthreads();                            // done reading Qs as Q
    US* Pw = &Qs[wv * (16 * 64)];               // per-wave P tile [16 m][64 t], swz &7

    f32x4 o[8];
    const f32x4 z = {0.f, 0.f, 0.f, 0.f};
#pragma unroll
    for (int j = 0; j < 8; ++j) o[j] = z;
    float l4[4] = {0.f, 0.f, 0.f, 0.f};

    const US* mrow  = Mk + (size_t)(b_ * 512 + q0 + wq + g * 4) * 4096 + c15;
    const US* Kbase = Kh + (size_t)bh * 4096 * 128;
    const US* Vbase = VTh + (size_t)bh * 128 * 4096;

    for (int t = 0; t < 16; ++t) {
        int kv0 = kvbase + t * 64;
        __syncthreads();
        const US* Kb = Kbase + (size_t)kv0 * 128;
#pragma unroll
        for (int q = 0; q < 4; ++q) {
            int eb = (q * 256 + wv * 64) * 8;
            int r = (eb >> 7) + (ln >> 4);
            int sw = (ln & 15) ^ (r & 15);
            gl_lds16(Kb + (size_t)r * 128 + sw * 8, &Ks[eb]);
        }
#pragma unroll
        for (int q = 0; q < 4; ++q) {
            int eb = (q * 256 + wv * 64) * 8;
            int r = (eb >> 6) + (ln >> 3);      // 8 rows per instr
            int sw = (ln & 7) ^ (r & 7);
            gl_lds16(Vbase + (size_t)r * 4096 + kv0 + sw * 8, &Vs[eb]);
        }
        US mv[4][4];
#pragma unroll
        for (int r2 = 0; r2 < 4; ++r2) {
            const US* pr = mrow + (size_t)r2 * 4096 + kv0;
#pragma unroll
            for (int j = 0; j < 4; ++j) mv[r2][j] = pr[j * 16];
        }
        __syncthreads();

        // S = Q K^T
        f32x4 s[4];
#pragma unroll
        for (int j = 0; j < 4; ++j) s[j] = z;
#pragma unroll
        for (int ks = 0; ks < 4; ++ks) {
#pragma unroll
            for (int j = 0; j < 4; ++j) {
                int p = (ks * 4 + g) ^ c15;     // (j*16+c15)&15 == c15
                bf16x8 kb = ldv8(&Ks[(j * 16 + c15) * 128 + p * 8]);
                s[j] = __builtin_amdgcn_mfma_f32_16x16x32_bf16(qa[ks], kb, s[j], 0, 0, 0);
            }
        }
        // p = exp(s)*mask; accumulate l; store P swizzled ([m][t], chunk^=(m&7))
#pragma unroll
        for (int j = 0; j < 4; ++j) {
#pragma unroll
            for (int r2 = 0; r2 < 4; ++r2) {
                float pp = __expf(s[j][r2]);
                pp = mv[r2][j] ? pp : 0.0f;
                l4[r2] += pp;
                int m = g * 4 + r2;
                int c = (c15 >> 3) + j * 2;
                Pw[m * 64 + ((c ^ (m & 7)) * 8) + (c15 & 7)] = f2bf(pp);
            }
        }
        // O += P V
#pragma unroll
        for (int ks = 0; ks < 2; ++ks) {
            int pp_ = (ks * 4 + g) ^ (c15 & 7);
            bf16x8 pa = ldv8(&Pw[c15 * 64 + pp_ * 8]);
#pragma unroll
            for (int j = 0; j < 8; ++j) {
                int pv = (ks * 4 + g) ^ (c15 & 7);   // (j*16+c15)&7 == c15&7
                bf16x8 vb = ldv8(&Vs[(j * 16 + c15) * 64 + pv * 8]);
                o[j] = __builtin_amdgcn_mfma_f32_16x16x32_bf16(pa, vb, o[j], 0, 0, 0);
            }
        }
    }

    // reduce l over the 16 c15 lanes; write partials
#pragma unroll
    for (int r = 0; r < 4; ++r) {
        float l = l4[r];
        l += __shfl_xor(l, 1); l += __shfl_xor(l, 2);
        l += __shfl_xor(l, 4); l += __shfl_xor(l, 8);
        l4[r] = l;
    }
    size_t obase = ((((size_t)sp * 32 + bh) * 8 + qt) * 64 + wq) * 128;
#pragma unroll
    for (int j = 0; j < 8; ++j)
#pragma unroll
        for (int r = 0; r < 4; ++r)
            Opart[obase + (size_t)(g * 4 + r) * 128 + j * 16 + c15] = o[j][r];
    if (c15 == 0) {
#pragma unroll
        for (int r = 0; r < 4; ++r)
            Lpart[(((size_t)sp * 32 + bh) * 8 + qt) * 64 + wq + g * 4 + r] = l4[r];
    }
}

// ---------------- combine split-KV partials -> AO bf16 ----------------
__global__ void combine(const float* __restrict__ Opart, const float* __restrict__ Lpart,
                        US* __restrict__ AO) {
    const int bh = blockIdx.x >> 3, qt = blockIdx.x & 7;
    const int b_ = bh >> 3, h = bh & 7;
    const int tid = threadIdx.x;
    const size_t sstride = (size_t)32 * 8 * 64 * 128;
    const size_t lstride = (size_t)32 * 8 * 64;
    const size_t slice  = ((size_t)bh * 8 + qt) * 64 * 128;
    const size_t lslice = ((size_t)bh * 8 + qt) * 64;
#pragma unroll
    for (int i = 0; i < 8; ++i) {
        int p = tid + i * 256;                  // float4 index within 64x128 slice
        int row = p >> 5;
        float lsum = Lpart[lslice + row] + Lpart[lstride + lslice + row]
                   + Lpart[2 * lstride + lslice + row] + Lpart[3 * lstride + lslice + row];
        float inv = lsum > 0.f ? 1.f / lsum : 0.f;
        float4 a = *((const float4*)(Opart + slice) + p);
        float4 b = *((const float4*)(Opart + sstride + slice) + p);
        float4 c = *((const float4*)(Opart + 2 * sstride + slice) + p);
        float4 d = *((const float4*)(Opart + 3 * sstride + slice) + p);
        float x = (a.x + b.x + c.x + d.x) * inv;
        float y = (a.y + b.y + c.y + d.y) * inv;
        float z2 = (a.z + b.z + c.z + d.z) * inv;
        float w = (a.w + b.w + c.w + d.w) * inv;
        int d_ = (p & 31) * 4;
        int trow = qt * 64 + row;
        us4 ov = { f2bf(x), f2bf(y), f2bf(z2), f2bf(w) };
        *(us4*)(AO + ((size_t)(b_ * 512 + trow)) * 1024 + h * 128 + d_) = ov;
    }
}

// ---------------- launch ----------------
extern "C" void kernel_launch(void* const* d_in, const int* in_sizes, int n_in,
                              void* d_out, int out_size, void* d_ws, size_t ws_size,
                              hipStream_t stream) {
    (void)in_sizes; (void)n_in; (void)out_size; (void)ws_size;
    const float* Xq  = (const float*)d_in[0];
    const float* Xkv = (const float*)d_in[1];
    const int*   Mi  = (const int*)d_in[2];
    const float* Wq  = (const float*)d_in[3];
    const float* bq  = (const float*)d_in[4];
    const float* Wk  = (const float*)d_in[5];
    const float* bk  = (const float*)d_in[6];
    const float* Wv  = (const float*)d_in[7];
    const float* bv  = (const float*)d_in[8];
    const float* Wo  = (const float*)d_in[9];
    const float* bo  = (const float*)d_in[10];
    float* out = (float*)d_out;

    char* p = (char*)d_ws;
    US* XqB  = (US*)p; p += (size_t)2048 * 1024 * 2;
    US* XkvB = (US*)p; p += (size_t)16384 * 1024 * 2;
    US* WT   = (US*)p; p += (size_t)4 * 1024 * 1024 * 2;
    US* MB   = (US*)p; p += (size_t)4 * 512 * 4096 * 2;
    US* Qh   = (US*)p; p += (size_t)2048 * 1024 * 2;
    US* Kh   = (US*)p; p += (size_t)16384 * 1024 * 2;
    US* Vh   = (US*)p; p += (size_t)16384 * 1024 * 2;
    US* VTh  = (US*)p; p += (size_t)16384 * 1024 * 2;
    US* AO   = (US*)p; p += (size_t)2048 * 1024 * 2;
    // aliased scratch (stream-ordered safe):
    float* Opart = (float*)XkvB;  // 33.5 MB; XkvB last read by gemm_kv, flash runs after
    float* Lpart = (float*)Vh;    // 256 KB; Vh last read by v_transpose, flash runs after

    conv_bf16<<<2048, 256, 0, stream>>>(Xq, XqB, 2048 * 1024 / 4);
    conv_bf16<<<16384, 256, 0, stream>>>(Xkv, XkvB, 16384 * 1024 / 4);
    conv_mask<<<8192, 256, 0, stream>>>(Mi, MB, 4 * 512 * 4096 / 4);
    wt_conv<<<dim3(32, 32, 4), 256, 0, stream>>>(Wq, Wk, Wv, Wo, WT);

    // Q projection: fold softmax scale 1/sqrt(128) into Q
    gemm_bt<0><<<dim3(16, 8), 256, 0, stream>>>(XqB, WT, bq, Qh, 9, 0.08838834764831843f);
    gemm_kv<<<dim3(128, 8), 256, 0, stream>>>(XkvB, WT + 1048576, WT + 2097152,
                                              bk, bv, Kh, Vh);
    v_transpose<<<dim3(128, 4, 32), 256, 0, stream>>>(Vh, VTh);
    flash<<<dim3(8, 32, 4), 256, 0, stream>>>(Qh, Kh, VTh, MB, Opart, Lpart);
    combine<<<256, 256, 0, stream>>>(Opart, Lpart, AO);
    gemm_bt<1><<<dim3(16, 8), 256, 0, stream>>>(AO, WT + 3145728, bo, out, 0, 1.0f);
}

// Round 3
// 353.590 us; speedup vs baseline: 1.3809x; 1.0811x over previous
//
#include <hip/hip_runtime.h>
#include <cstdint>
#include <cstddef>

typedef unsigned short US;
typedef __bf16 bf16_t;
typedef bf16_t bf16x8 __attribute__((ext_vector_type(8)));
typedef float  f32x4  __attribute__((ext_vector_type(4)));
typedef US     us8    __attribute__((ext_vector_type(8)));
typedef US     us4    __attribute__((ext_vector_type(4)));

#define AS1 __attribute__((address_space(1)))
#define AS3 __attribute__((address_space(3)))

__device__ __forceinline__ void gl_lds16(const void* g, void* l) {
    __builtin_amdgcn_global_load_lds((AS1 unsigned int*)(size_t)g,
                                     (AS3 unsigned int*)l, 16, 0, 0);
}

__device__ __forceinline__ US f2bf(float f) {
    unsigned u = __builtin_bit_cast(unsigned, f);
    u += 0x7FFFu + ((u >> 16) & 1u);   // RNE (inputs finite)
    return (US)(u >> 16);
}

__device__ __forceinline__ bf16x8 ldv8(const US* p) {
    return __builtin_bit_cast(bf16x8, *(const us8*)p);
}

// ---------------- fused converts: Xq, Xkv -> bf16; mask -> us 0/1 ----------------
__global__ void prep(const float* __restrict__ Xq, const float* __restrict__ Xkv,
                     const int* __restrict__ Mi, US* __restrict__ XqB,
                     US* __restrict__ XkvB, US* __restrict__ MB) {
    int b = blockIdx.x, tid = threadIdx.x;
    if (b < 2048) {
        int i = b * 256 + tid;
        float4 f = ((const float4*)Xq)[i];
        us4 o = { f2bf(f.x), f2bf(f.y), f2bf(f.z), f2bf(f.w) };
        ((us4*)XqB)[i] = o;
    } else if (b < 18432) {
        int i = (b - 2048) * 256 + tid;
        float4 f = ((const float4*)Xkv)[i];
        us4 o = { f2bf(f.x), f2bf(f.y), f2bf(f.z), f2bf(f.w) };
        ((us4*)XkvB)[i] = o;
    } else {
        int i = (b - 18432) * 256 + tid;
        int4 m = ((const int4*)Mi)[i];
        us4 o = { (US)(m.x ? 1 : 0), (US)(m.y ? 1 : 0),
                  (US)(m.z ? 1 : 0), (US)(m.w ? 1 : 0) };
        ((us4*)MB)[i] = o;
    }
}

// ---------------- weight transpose+convert: W[k][n] f32 -> WT[n][k] bf16 ----------------
__global__ void wt_conv(const float* __restrict__ Wq, const float* __restrict__ Wk,
                        const float* __restrict__ Wv, const float* __restrict__ Wo,
                        US* __restrict__ outbase) {
    const float* W = (blockIdx.z == 0) ? Wq : (blockIdx.z == 1) ? Wk
                   : (blockIdx.z == 2) ? Wv : Wo;
    US* WT = outbase + (size_t)blockIdx.z * 1024 * 1024;
    __shared__ float t[32][33];
    int tx = threadIdx.x & 31, ty = threadIdx.x >> 5;
    int x = blockIdx.x * 32 + tx;
#pragma unroll
    for (int r = 0; r < 4; ++r)
        t[ty + r * 8][tx] = W[(size_t)(blockIdx.y * 32 + ty + r * 8) * 1024 + x];
    __syncthreads();
    int nx = blockIdx.y * 32 + tx;
#pragma unroll
    for (int r = 0; r < 4; ++r)
        WT[(size_t)(blockIdx.x * 32 + ty + r * 8) * 1024 + nx] = f2bf(t[tx][ty + r * 8]);
}

// ---------------- V transpose: [bh][4096][128] -> [bh][128][4096] (bf16) ----------------
__global__ void v_transpose(const US* __restrict__ Vh, US* __restrict__ VTh) {
    __shared__ US t[32][33];
    int tx = threadIdx.x & 31, ty = threadIdx.x >> 5;
    size_t base = (size_t)blockIdx.z * 4096 * 128;
    int t0 = blockIdx.x * 32, d0 = blockIdx.y * 32;
#pragma unroll
    for (int r = 0; r < 4; ++r)
        t[ty + r * 8][tx] = Vh[base + (size_t)(t0 + ty + r * 8) * 128 + d0 + tx];
    __syncthreads();
#pragma unroll
    for (int r = 0; r < 4; ++r)
        VTh[base + (size_t)(d0 + ty + r * 8) * 4096 + t0 + tx] = t[tx][ty + r * 8];
}

// ---------------- GEMM: C[M,1024] = A[M,1024]bf16 @ Bt[1024,1024]^T + bias ----------------
template <int MODE>
__global__ __launch_bounds__(256, 2)
void gemm_bt(const US* __restrict__ A, const US* __restrict__ Bt,
             const float* __restrict__ bias, void* __restrict__ out,
             int tlog2, float scale) {
    constexpr int K = 1024, N = 1024, BK = 64;
    __shared__ US As[128 * BK];
    __shared__ US Bs[128 * BK];
    const int tid = threadIdx.x;
    const int wv = tid >> 6, ln = tid & 63;
    const int g = ln >> 4, c15 = ln & 15;
    const int m0 = blockIdx.x * 128, n0 = blockIdx.y * 128;
    const int wm = (wv & 1) * 64, wn = (wv >> 1) * 64;

    f32x4 acc[4][4];
    const f32x4 z = {0.f, 0.f, 0.f, 0.f};
#pragma unroll
    for (int i = 0; i < 4; ++i)
#pragma unroll
        for (int j = 0; j < 4; ++j) acc[i][j] = z;

    const US* Ab = A + (size_t)m0 * K;
    const US* Bb = Bt + (size_t)n0 * K;

    for (int k0 = 0; k0 < K; k0 += BK) {
        __syncthreads();
#pragma unroll
        for (int q = 0; q < 4; ++q) {
            int eb = (q * 256 + wv * 64) * 8;
            int r = (eb >> 6) + (ln >> 3);
            int sw = (ln & 7) ^ (r & 7);
            gl_lds16(Ab + (size_t)r * K + k0 + sw * 8, &As[eb]);
            gl_lds16(Bb + (size_t)r * K + k0 + sw * 8, &Bs[eb]);
        }
        __syncthreads();
#pragma unroll
        for (int ks = 0; ks < 2; ++ks) {
            bf16x8 a[4], b[4];
#pragma unroll
            for (int i = 0; i < 4; ++i) {
                int p = (ks * 4 + g) ^ (c15 & 7);
                a[i] = ldv8(&As[(wm + i * 16 + c15) * BK + p * 8]);
            }
#pragma unroll
            for (int j = 0; j < 4; ++j) {
                int p = (ks * 4 + g) ^ (c15 & 7);
                b[j] = ldv8(&Bs[(wn + j * 16 + c15) * BK + p * 8]);
            }
#pragma unroll
            for (int i = 0; i < 4; ++i)
#pragma unroll
                for (int j = 0; j < 4; ++j)
                    acc[i][j] = __builtin_amdgcn_mfma_f32_16x16x32_bf16(a[i], b[j], acc[i][j], 0, 0, 0);
        }
    }

#pragma unroll
    for (int i = 0; i < 4; ++i) {
#pragma unroll
        for (int j = 0; j < 4; ++j) {
            int col = n0 + wn + j * 16 + c15;
            float bvv = bias[col];
#pragma unroll
            for (int r = 0; r < 4; ++r) {
                int row = m0 + wm + i * 16 + g * 4 + r;
                float v = (acc[i][j][r] + bvv) * scale;
                if (MODE == 0) {
                    int b_ = row >> tlog2;
                    int t = row & ((1 << tlog2) - 1);
                    int h = col >> 7, d = col & 127;
                    ((US*)out)[(((size_t)(b_ * 8 + h) << tlog2) + t) * 128 + d] = f2bf(v);
                } else {
                    ((float*)out)[(size_t)row * N + col] = v;
                }
            }
        }
    }
}

// ---------------- fused K+V projection GEMM (shared A staging) ----------------
__global__ __launch_bounds__(256, 2)
void gemm_kv(const US* __restrict__ A, const US* __restrict__ BtK,
             const US* __restrict__ BtV, const float* __restrict__ bk,
             const float* __restrict__ bv, US* __restrict__ Kout,
             US* __restrict__ Vout) {
    constexpr int K = 1024, BK = 64;
    __shared__ US As[128 * BK];
    __shared__ US BsK[128 * BK];
    __shared__ US BsV[128 * BK];
    const int tid = threadIdx.x;
    const int wv = tid >> 6, ln = tid & 63;
    const int g = ln >> 4, c15 = ln & 15;
    const int m0 = blockIdx.x * 128, n0 = blockIdx.y * 128;
    const int wm = (wv & 1) * 64, wn = (wv >> 1) * 64;

    f32x4 aK[4][4], aV[4][4];
    const f32x4 z = {0.f, 0.f, 0.f, 0.f};
#pragma unroll
    for (int i = 0; i < 4; ++i)
#pragma unroll
        for (int j = 0; j < 4; ++j) { aK[i][j] = z; aV[i][j] = z; }

    const US* Ab  = A   + (size_t)m0 * K;
    const US* BbK = BtK + (size_t)n0 * K;
    const US* BbV = BtV + (size_t)n0 * K;

    for (int k0 = 0; k0 < K; k0 += BK) {
        __syncthreads();
#pragma unroll
        for (int q = 0; q < 4; ++q) {
            int eb = (q * 256 + wv * 64) * 8;
            int r = (eb >> 6) + (ln >> 3);
            int sw = (ln & 7) ^ (r & 7);
            gl_lds16(Ab  + (size_t)r * K + k0 + sw * 8, &As[eb]);
            gl_lds16(BbK + (size_t)r * K + k0 + sw * 8, &BsK[eb]);
            gl_lds16(BbV + (size_t)r * K + k0 + sw * 8, &BsV[eb]);
        }
        __syncthreads();
#pragma unroll
        for (int ks = 0; ks < 2; ++ks) {
            bf16x8 a[4], bK[4], bV[4];
#pragma unroll
            for (int i = 0; i < 4; ++i) {
                int p = (ks * 4 + g) ^ (c15 & 7);
                a[i] = ldv8(&As[(wm + i * 16 + c15) * BK + p * 8]);
            }
#pragma unroll
            for (int j = 0; j < 4; ++j) {
                int p = (ks * 4 + g) ^ (c15 & 7);
                bK[j] = ldv8(&BsK[(wn + j * 16 + c15) * BK + p * 8]);
                bV[j] = ldv8(&BsV[(wn + j * 16 + c15) * BK + p * 8]);
            }
#pragma unroll
            for (int i = 0; i < 4; ++i)
#pragma unroll
                for (int j = 0; j < 4; ++j) {
                    aK[i][j] = __builtin_amdgcn_mfma_f32_16x16x32_bf16(a[i], bK[j], aK[i][j], 0, 0, 0);
                    aV[i][j] = __builtin_amdgcn_mfma_f32_16x16x32_bf16(a[i], bV[j], aV[i][j], 0, 0, 0);
                }
        }
    }

#pragma unroll
    for (int i = 0; i < 4; ++i) {
#pragma unroll
        for (int j = 0; j < 4; ++j) {
            int col = n0 + wn + j * 16 + c15;
            float bkv = bk[col], bvv = bv[col];
            int h = col >> 7, d = col & 127;
#pragma unroll
            for (int r = 0; r < 4; ++r) {
                int row = m0 + wm + i * 16 + g * 4 + r;
                int b_ = row >> 12, t = row & 4095;
                size_t oi = (((size_t)(b_ * 8 + h) << 12) + t) * 128 + d;
                Kout[oi] = f2bf(aK[i][j][r] + bkv);
                Vout[oi] = f2bf(aV[i][j][r] + bvv);
            }
        }
    }
}

// ---------------- flash attention v3: S^T form, O^T output, split-KV ----------------
// grid (4 qt of 128 q, 32 bh, 6 sp). 256 thr = 4 waves x 32 q-rows.
// S^T = K Q^T (C-layout: col=q, row=kv). Q frags direct from global (B-operand).
// P kept per-wave in LDS [q32][kv64]: us4 writes, b128 B-operand reads.
// O^T = V^T P^T accumulated in regs; partials (un-normalized) to Opart [sp][bh][d][q].
__global__ __launch_bounds__(256, 3)
void flash(const US* __restrict__ Qh, const US* __restrict__ Kh,
           const US* __restrict__ VTh, const US* __restrict__ Mk,
           float* __restrict__ Opart, float* __restrict__ Lpart) {
    __shared__ US Ks[64 * 128];        // [kv][d] 16KB, swz (r&15)
    __shared__ US Vs[128 * 64];        // [d][kv] 16KB, swz (r&7)
    __shared__ US Ps[4][32 * 64];      // per-wave P [q][kv] 16KB, 16B-chunk swz (q&7)
    const int tid = threadIdx.x, wv = tid >> 6, ln = tid & 63;
    const int g = ln >> 4, c15 = ln & 15;
    const int qt = blockIdx.x, qbase = qt * 128;
    const int bh = blockIdx.y, b_ = bh >> 3;
    const int sp = blockIdx.z;
    const int t0 = (sp < 4) ? sp * 11 : 44 + (sp - 4) * 10;   // tiles of 64 kv
    const int nt = (sp < 4) ? 11 : 10;
    const int wq = wv * 32;

    // Q fragments (B-operand: lane holds Q[q=...+c15][k-chunk]) straight from global
    bf16x8 qa[2][4];
#pragma unroll
    for (int ib = 0; ib < 2; ++ib) {
        const US* qrow = Qh + ((size_t)bh * 512 + qbase + wq + ib * 16 + c15) * 128;
#pragma unroll
        for (int ks = 0; ks < 4; ++ks)
            qa[ib][ks] = ldv8(qrow + ks * 32 + g * 8);
    }

    f32x4 o[8][2];
    const f32x4 z = {0.f, 0.f, 0.f, 0.f};
#pragma unroll
    for (int d = 0; d < 8; ++d) { o[d][0] = z; o[d][1] = z; }
    float l2[2] = {0.f, 0.f};

    const US* mp[2];
    mp[0] = Mk + (size_t)(b_ * 512 + qbase + wq + c15) * 4096;
    mp[1] = mp[0] + (size_t)16 * 4096;
    const US* Kbase = Kh + ((size_t)bh * 4096 + (size_t)t0 * 64) * 128;
    const US* Vbase = VTh + (size_t)bh * 128 * 4096;
    US* Pw = &Ps[wv][0];

    for (int t = 0; t < nt; ++t) {
        int kv0 = (t0 + t) * 64;
        __syncthreads();
        const US* Kb = Kbase + (size_t)t * 64 * 128;
#pragma unroll
        for (int q = 0; q < 4; ++q) {               // K tile: rows kv, 128 d
            int eb = (q * 256 + wv * 64) * 8;
            int r = (eb >> 7) + (ln >> 4);
            int sw = (ln & 15) ^ (r & 15);
            gl_lds16(Kb + (size_t)r * 128 + sw * 8, &Ks[eb]);
        }
#pragma unroll
        for (int q = 0; q < 4; ++q) {               // V^T tile: rows d, 64 kv
            int eb = (q * 256 + wv * 64) * 8;
            int r = (eb >> 6) + (ln >> 3);
            int sw = (ln & 7) ^ (r & 7);
            gl_lds16(Vbase + (size_t)r * 4096 + kv0 + sw * 8, &Vs[eb]);
        }
        us4 mv[2][4];
#pragma unroll
        for (int ib = 0; ib < 2; ++ib)
#pragma unroll
            for (int kb = 0; kb < 4; ++kb)
                mv[ib][kb] = *(const us4*)(mp[ib] + kv0 + kb * 16 + g * 4);
        __syncthreads();

        // S^T block-row per kvb: 16 kv x 32 q, then exp/mask -> P LDS
#pragma unroll
        for (int kb = 0; kb < 4; ++kb) {
            f32x4 s0 = z, s1 = z;
#pragma unroll
            for (int ks = 0; ks < 4; ++ks) {
                bf16x8 kf = ldv8(&Ks[(kb * 16 + c15) * 128 + (((ks * 4 + g) ^ c15) * 8)]);
                s0 = __builtin_amdgcn_mfma_f32_16x16x32_bf16(kf, qa[0][ks], s0, 0, 0, 0);
                s1 = __builtin_amdgcn_mfma_f32_16x16x32_bf16(kf, qa[1][ks], s1, 0, 0, 0);
            }
            int cw = kb * 4 + g;
#pragma unroll
            for (int ib = 0; ib < 2; ++ib) {
                f32x4 sv = ib ? s1 : s0;
                float p0 = mv[ib][kb].x ? __expf(sv[0]) : 0.f;
                float p1 = mv[ib][kb].y ? __expf(sv[1]) : 0.f;
                float p2 = mv[ib][kb].z ? __expf(sv[2]) : 0.f;
                float p3 = mv[ib][kb].w ? __expf(sv[3]) : 0.f;
                l2[ib] += (p0 + p1) + (p2 + p3);
                int q = ib * 16 + c15;
                US* wp = Pw + q * 64 + (((cw >> 1) ^ (q & 7)) * 8) + (cw & 1) * 4;
                us4 pv = { f2bf(p0), f2bf(p1), f2bf(p2), f2bf(p3) };
                *(us4*)wp = pv;
            }
        }

        // O^T += V^T P^T
#pragma unroll
        for (int ks = 0; ks < 2; ++ks) {
            bf16x8 pf[2];
#pragma unroll
            for (int ib = 0; ib < 2; ++ib) {
                int q = ib * 16 + c15;
                pf[ib] = ldv8(&Pw[q * 64 + (((ks * 4 + g) ^ (q & 7)) * 8)]);
            }
#pragma unroll
            for (int d = 0; d < 8; ++d) {
                bf16x8 vf = ldv8(&Vs[(d * 16 + c15) * 64 + (((ks * 4 + g) ^ (c15 & 7)) * 8)]);
                o[d][0] = __builtin_amdgcn_mfma_f32_16x16x32_bf16(vf, pf[0], o[d][0], 0, 0, 0);
                o[d][1] = __builtin_amdgcn_mfma_f32_16x16x32_bf16(vf, pf[1], o[d][1], 0, 0, 0);
            }
        }
    }

    // l: reduce over the 4 g-lanes sharing c15
    float lf[2];
#pragma unroll
    for (int ib = 0; ib < 2; ++ib) {
        float l = l2[ib];
        l += __shfl_xor(l, 16); l += __shfl_xor(l, 32);
        lf[ib] = l;
    }
    if (ln < 16) {
        size_t lb = ((size_t)sp * 32 + bh) * 512 + qbase + wq + c15;
        Lpart[lb] = lf[0];
        Lpart[lb + 16] = lf[1];
    }
    // Opart [sp][bh][d=128][q=512], un-normalized
    float* Ob = Opart + (((size_t)sp * 32 + bh) * 128 + g * 4) * 512 + qbase + wq + c15;
#pragma unroll
    for (int d = 0; d < 8; ++d)
#pragma unroll
        for (int r = 0; r < 4; ++r) {
            Ob[(size_t)(d * 16 + r) * 512] = o[d][0][r];
            Ob[(size_t)(d * 16 + r) * 512 + 16] = o[d][1][r];
        }
}

// ---------------- combine: sum 6 splits, normalize, transpose -> AO bf16 ----------------
__global__ void combine(const float* __restrict__ Opart, const float* __restrict__ Lpart,
                        US* __restrict__ AO) {
    __shared__ float linv[128];
    __shared__ float T[128 * 33];
    const int qt = blockIdx.x, bh = blockIdx.y;
    const int b_ = bh >> 3, h = bh & 7;
    const int tid = threadIdx.x;
    const size_t spstride = (size_t)32 * 128 * 512;

    if (tid < 128) {
        float s = 0.f;
#pragma unroll
        for (int sp = 0; sp < 6; ++sp)
            s += Lpart[((size_t)sp * 32 + bh) * 512 + qt * 128 + tid];
        linv[tid] = (s > 0.f) ? 1.f / s : 0.f;
    }
    __syncthreads();

    for (int ds0 = 0; ds0 < 128; ds0 += 32) {
        if (ds0) __syncthreads();
#pragma unroll
        for (int it = 0; it < 4; ++it) {
            int d = ds0 + (tid >> 5) + it * 8, qc = tid & 31;
            const float* base = Opart + ((size_t)bh * 128 + d) * 512 + qt * 128 + qc * 4;
            float4 a = {0.f, 0.f, 0.f, 0.f};
#pragma unroll
            for (int sp = 0; sp < 6; ++sp) {
                float4 v = *(const float4*)(base + sp * spstride);
                a.x += v.x; a.y += v.y; a.z += v.z; a.w += v.w;
            }
            int dd = d - ds0;
            T[(qc * 4 + 0) * 33 + dd] = a.x * linv[qc * 4 + 0];
            T[(qc * 4 + 1) * 33 + dd] = a.y * linv[qc * 4 + 1];
            T[(qc * 4 + 2) * 33 + dd] = a.z * linv[qc * 4 + 2];
            T[(qc * 4 + 3) * 33 + dd] = a.w * linv[qc * 4 + 3];
        }
        __syncthreads();
#pragma unroll
        for (int it = 0; it < 4; ++it) {
            int idx = tid + it * 256;
            int q = idx >> 3, c = idx & 7;
            const float* tr = &T[q * 33 + c * 4];
            us4 ov = { f2bf(tr[0]), f2bf(tr[1]), f2bf(tr[2]), f2bf(tr[3]) };
            *(us4*)(AO + ((size_t)(b_ * 512 + qt * 128 + q)) * 1024 + h * 128 + ds0 + c * 4) = ov;
        }
    }
}

// ---------------- launch ----------------
extern "C" void kernel_launch(void* const* d_in, const int* in_sizes, int n_in,
                              void* d_out, int out_size, void* d_ws, size_t ws_size,
                              hipStream_t stream) {
    (void)in_sizes; (void)n_in; (void)out_size; (void)ws_size;
    const float* Xq  = (const float*)d_in[0];
    const float* Xkv = (const float*)d_in[1];
    const int*   Mi  = (const int*)d_in[2];
    const float* Wq  = (const float*)d_in[3];
    const float* bq  = (const float*)d_in[4];
    const float* Wk  = (const float*)d_in[5];
    const float* bk  = (const float*)d_in[6];
    const float* Wv  = (const float*)d_in[7];
    const float* bv  = (const float*)d_in[8];
    const float* Wo  = (const float*)d_in[9];
    const float* bo  = (const float*)d_in[10];
    float* out = (float*)d_out;

    // ws layout (order matters for aliasing):
    char* p = (char*)d_ws;
    US* WT   = (US*)p; p += (size_t)4 * 1024 * 1024 * 2;     // 8.4 MB, live to end
    US* AO   = (US*)p; p += (size_t)2048 * 1024 * 2;         // 4 MB
    US* XqB  = (US*)p; p += (size_t)2048 * 1024 * 2;         // 4 MB, dead after Q-proj
    US* Qh   = (US*)p; p += (size_t)2048 * 1024 * 2;         // 4 MB
    US* Kh   = (US*)p; p += (size_t)16384 * 1024 * 2;        // 33.5 MB
    US* VTh  = (US*)p; p += (size_t)16384 * 1024 * 2;        // 33.5 MB
    US* XkvB = (US*)p; p += (size_t)16384 * 1024 * 2;        // 33.5 MB, dead after gemm_kv
    US* Vh   = (US*)p; p += (size_t)16384 * 1024 * 2;        // 33.5 MB, dead after v_transpose
    US* MB   = (US*)p; p += (size_t)4 * 512 * 4096 * 2;      // 16.8 MB, live in flash
    float* Opart = (float*)XkvB;   // 50.3 MB spans XkvB+Vh (both dead when flash runs)
    float* Lpart = (float*)XqB;    // 393 KB

    prep<<<26624, 256, 0, stream>>>(Xq, Xkv, Mi, XqB, XkvB, MB);
    wt_conv<<<dim3(32, 32, 4), 256, 0, stream>>>(Wq, Wk, Wv, Wo, WT);

    // Q projection: fold softmax scale 1/sqrt(128) into Q
    gemm_bt<0><<<dim3(16, 8), 256, 0, stream>>>(XqB, WT, bq, Qh, 9, 0.08838834764831843f);
    gemm_kv<<<dim3(128, 8), 256, 0, stream>>>(XkvB, WT + 1048576, WT + 2097152,
                                              bk, bv, Kh, Vh);
    v_transpose<<<dim3(128, 4, 32), 256, 0, stream>>>(Vh, VTh);
    flash<<<dim3(4, 32, 6), 256, 0, stream>>>(Qh, Kh, VTh, MB, Opart, Lpart);
    combine<<<dim3(4, 32), 256, 0, stream>>>(Opart, Lpart, AO);
    gemm_bt<1><<<dim3(16, 8), 256, 0, stream>>>(AO, WT + 3145728, bo, out, 0, 1.0f);
}

// Round 4
// 351.916 us; speedup vs baseline: 1.3875x; 1.0048x over previous
//
#include <hip/hip_runtime.h>
#include <cstdint>
#include <cstddef>

typedef unsigned short US;
typedef __bf16 bf16_t;
typedef bf16_t bf16x8 __attribute__((ext_vector_type(8)));
typedef float  f32x4  __attribute__((ext_vector_type(4)));
typedef US     us8    __attribute__((ext_vector_type(8)));
typedef US     us4    __attribute__((ext_vector_type(4)));

#define AS1 __attribute__((address_space(1)))
#define AS3 __attribute__((address_space(3)))

__device__ __forceinline__ void gl_lds16(const void* g, void* l) {
    __builtin_amdgcn_global_load_lds((AS1 unsigned int*)(size_t)g,
                                     (AS3 unsigned int*)l, 16, 0, 0);
}

__device__ __forceinline__ US f2bf(float f) {
    unsigned u = __builtin_bit_cast(unsigned, f);
    u += 0x7FFFu + ((u >> 16) & 1u);   // RNE (inputs finite)
    return (US)(u >> 16);
}

__device__ __forceinline__ bf16x8 ldv8(const US* p) {
    return __builtin_bit_cast(bf16x8, *(const us8*)p);
}

// ---------------- fused converts: Xq, Xkv -> bf16; mask -> bitmask ----------------
__global__ void prep(const float* __restrict__ Xq, const float* __restrict__ Xkv,
                     const int* __restrict__ Mi, US* __restrict__ XqB,
                     US* __restrict__ XkvB, unsigned long long* __restrict__ MBits) {
    int b = blockIdx.x, tid = threadIdx.x;
    if (b < 2048) {
        int i = b * 256 + tid;
        float4 f = ((const float4*)Xq)[i];
        us4 o = { f2bf(f.x), f2bf(f.y), f2bf(f.z), f2bf(f.w) };
        ((us4*)XqB)[i] = o;
    } else if (b < 18432) {
        int i = (b - 2048) * 256 + tid;
        float4 f = ((const float4*)Xkv)[i];
        us4 o = { f2bf(f.x), f2bf(f.y), f2bf(f.z), f2bf(f.w) };
        ((us4*)XkvB)[i] = o;
    } else {
        int i = (b - 18432) * 256 + tid;   // one int per thread; wave = 64 consecutive kv
        int m = Mi[i];
        unsigned long long bits = __ballot(m != 0);
        if ((tid & 63) == 0) MBits[i >> 6] = bits;
    }
}

// ---------------- weight transpose+convert: W[k][n] f32 -> WT[n][k] bf16 ----------------
__global__ void wt_conv(const float* __restrict__ Wq, const float* __restrict__ Wk,
                        const float* __restrict__ Wv, const float* __restrict__ Wo,
                        US* __restrict__ outbase) {
    const float* W = (blockIdx.z == 0) ? Wq : (blockIdx.z == 1) ? Wk
                   : (blockIdx.z == 2) ? Wv : Wo;
    US* WT = outbase + (size_t)blockIdx.z * 1024 * 1024;
    __shared__ float t[32][33];
    int tx = threadIdx.x & 31, ty = threadIdx.x >> 5;
    int x = blockIdx.x * 32 + tx;
#pragma unroll
    for (int r = 0; r < 4; ++r)
        t[ty + r * 8][tx] = W[(size_t)(blockIdx.y * 32 + ty + r * 8) * 1024 + x];
    __syncthreads();
    int nx = blockIdx.y * 32 + tx;
#pragma unroll
    for (int r = 0; r < 4; ++r)
        WT[(size_t)(blockIdx.x * 32 + ty + r * 8) * 1024 + nx] = f2bf(t[tx][ty + r * 8]);
}

// ---------------- GEMM: C[M,1024] = A[M,1024]bf16 @ Bt[1024,1024]^T + bias ----------------
// BM = 128 (4x4 acc/wave) or 64 (2x4 acc/wave, doubles grid for small M).
// MODE 0: bf16 split-heads out; MODE 1: fp32 row-major [M,1024]
template <int MODE, int BM>
__global__ __launch_bounds__(256, 2)
void gemm_bt(const US* __restrict__ A, const US* __restrict__ Bt,
             const float* __restrict__ bias, void* __restrict__ out,
             int tlog2, float scale) {
    constexpr int K = 1024, N = 1024, BK = 64;
    constexpr int MI = BM / 32;                  // acc rows per wave
    __shared__ US As[BM * BK];
    __shared__ US Bs[128 * BK];
    const int tid = threadIdx.x;
    const int wv = tid >> 6, ln = tid & 63;
    const int g = ln >> 4, c15 = ln & 15;
    const int m0 = blockIdx.x * BM, n0 = blockIdx.y * 128;
    const int wm = (wv & 1) * (BM / 2), wn = (wv >> 1) * 64;

    f32x4 acc[MI][4];
    const f32x4 z = {0.f, 0.f, 0.f, 0.f};
#pragma unroll
    for (int i = 0; i < MI; ++i)
#pragma unroll
        for (int j = 0; j < 4; ++j) acc[i][j] = z;

    const US* Ab = A + (size_t)m0 * K;
    const US* Bb = Bt + (size_t)n0 * K;

    for (int k0 = 0; k0 < K; k0 += BK) {
        __syncthreads();
#pragma unroll
        for (int q = 0; q < BM / 32; ++q) {
            int eb = (q * 256 + wv * 64) * 8;
            int r = (eb >> 6) + (ln >> 3);
            int sw = (ln & 7) ^ (r & 7);
            gl_lds16(Ab + (size_t)r * K + k0 + sw * 8, &As[eb]);
        }
#pragma unroll
        for (int q = 0; q < 4; ++q) {
            int eb = (q * 256 + wv * 64) * 8;
            int r = (eb >> 6) + (ln >> 3);
            int sw = (ln & 7) ^ (r & 7);
            gl_lds16(Bb + (size_t)r * K + k0 + sw * 8, &Bs[eb]);
        }
        __syncthreads();
#pragma unroll
        for (int ks = 0; ks < 2; ++ks) {
            bf16x8 a[MI], b[4];
#pragma unroll
            for (int i = 0; i < MI; ++i) {
                int p = (ks * 4 + g) ^ (c15 & 7);
                a[i] = ldv8(&As[(wm + i * 16 + c15) * BK + p * 8]);
            }
#pragma unroll
            for (int j = 0; j < 4; ++j) {
                int p = (ks * 4 + g) ^ (c15 & 7);
                b[j] = ldv8(&Bs[(wn + j * 16 + c15) * BK + p * 8]);
            }
#pragma unroll
            for (int i = 0; i < MI; ++i)
#pragma unroll
                for (int j = 0; j < 4; ++j)
                    acc[i][j] = __builtin_amdgcn_mfma_f32_16x16x32_bf16(a[i], b[j], acc[i][j], 0, 0, 0);
        }
    }

#pragma unroll
    for (int i = 0; i < MI; ++i) {
#pragma unroll
        for (int j = 0; j < 4; ++j) {
            int col = n0 + wn + j * 16 + c15;
            float bvv = bias[col];
#pragma unroll
            for (int r = 0; r < 4; ++r) {
                int row = m0 + wm + i * 16 + g * 4 + r;
                float v = (acc[i][j][r] + bvv) * scale;
                if (MODE == 0) {
                    int b_ = row >> tlog2;
                    int t = row & ((1 << tlog2) - 1);
                    int h = col >> 7, d = col & 127;
                    ((US*)out)[(((size_t)(b_ * 8 + h) << tlog2) + t) * 128 + d] = f2bf(v);
                } else {
                    ((float*)out)[(size_t)row * N + col] = v;
                }
            }
        }
    }
}

// ---------------- fused K+V projection GEMM; V written pre-transposed ----------------
// N-tile (128) == head dim, so each block owns one head's d-range: after the K-loop
// the V tile is transposed through LDS (reusing the staging buffer) and written as
// VT[bh][d][4096] rows -> v_transpose kernel eliminated.
__global__ __launch_bounds__(256, 2)
void gemm_kv(const US* __restrict__ A, const US* __restrict__ BtK,
             const US* __restrict__ BtV, const float* __restrict__ bk,
             const float* __restrict__ bv, US* __restrict__ Kout,
             US* __restrict__ VTout) {
    constexpr int K = 1024, BK = 64;
    __shared__ US lds[3 * 128 * BK];           // As | BsK | BsV ; epilogue: T[128*136]
    US* As  = lds;
    US* BsK = lds + 128 * BK;
    US* BsV = lds + 2 * 128 * BK;
    const int tid = threadIdx.x;
    const int wv = tid >> 6, ln = tid & 63;
    const int g = ln >> 4, c15 = ln & 15;
    const int m0 = blockIdx.x * 128, n0 = blockIdx.y * 128;
    const int wm = (wv & 1) * 64, wn = (wv >> 1) * 64;

    f32x4 aK[4][4], aV[4][4];
    const f32x4 z = {0.f, 0.f, 0.f, 0.f};
#pragma unroll
    for (int i = 0; i < 4; ++i)
#pragma unroll
        for (int j = 0; j < 4; ++j) { aK[i][j] = z; aV[i][j] = z; }

    const US* Ab  = A   + (size_t)m0 * K;
    const US* BbK = BtK + (size_t)n0 * K;
    const US* BbV = BtV + (size_t)n0 * K;

    for (int k0 = 0; k0 < K; k0 += BK) {
        __syncthreads();
#pragma unroll
        for (int q = 0; q < 4; ++q) {
            int eb = (q * 256 + wv * 64) * 8;
            int r = (eb >> 6) + (ln >> 3);
            int sw = (ln & 7) ^ (r & 7);
            gl_lds16(Ab  + (size_t)r * K + k0 + sw * 8, &As[eb]);
            gl_lds16(BbK + (size_t)r * K + k0 + sw * 8, &BsK[eb]);
            gl_lds16(BbV + (size_t)r * K + k0 + sw * 8, &BsV[eb]);
        }
        __syncthreads();
#pragma unroll
        for (int ks = 0; ks < 2; ++ks) {
            bf16x8 a[4], bK[4], bV[4];
#pragma unroll
            for (int i = 0; i < 4; ++i) {
                int p = (ks * 4 + g) ^ (c15 & 7);
                a[i] = ldv8(&As[(wm + i * 16 + c15) * BK + p * 8]);
            }
#pragma unroll
            for (int j = 0; j < 4; ++j) {
                int p = (ks * 4 + g) ^ (c15 & 7);
                bK[j] = ldv8(&BsK[(wn + j * 16 + c15) * BK + p * 8]);
                bV[j] = ldv8(&BsV[(wn + j * 16 + c15) * BK + p * 8]);
            }
#pragma unroll
            for (int i = 0; i < 4; ++i)
#pragma unroll
                for (int j = 0; j < 4; ++j) {
                    aK[i][j] = __builtin_amdgcn_mfma_f32_16x16x32_bf16(a[i], bK[j], aK[i][j], 0, 0, 0);
                    aV[i][j] = __builtin_amdgcn_mfma_f32_16x16x32_bf16(a[i], bV[j], aV[i][j], 0, 0, 0);
                }
        }
    }

    const int h = n0 >> 7;                      // == blockIdx.y
    const int b_ = m0 >> 12, tbase = m0 & 4095;

    // K epilogue: split-heads bf16 store (same as before)
#pragma unroll
    for (int i = 0; i < 4; ++i) {
#pragma unroll
        for (int j = 0; j < 4; ++j) {
            int col = n0 + wn + j * 16 + c15;
            float bkv = bk[col];
            int d = col & 127;
#pragma unroll
            for (int r = 0; r < 4; ++r) {
                int row = m0 + wm + i * 16 + g * 4 + r;
                int t = row & 4095;
                Kout[(((size_t)(b_ * 8 + h) << 12) + t) * 128 + d] = f2bf(aK[i][j][r] + bkv);
            }
        }
    }

    // V epilogue: transpose tile through LDS, write VT rows (256B/row, coalesced)
    __syncthreads();                            // staging reads all done; reuse lds
    US* T = lds;                                // [d 128][kv 128], stride 136 (16B-aligned rows)
#pragma unroll
    for (int i = 0; i < 4; ++i) {
#pragma unroll
        for (int j = 0; j < 4; ++j) {
            int dcol = wn + j * 16 + c15;
            float bvv = bv[n0 + dcol];
#pragma unroll
            for (int r = 0; r < 4; ++r) {
                int kvrow = wm + i * 16 + g * 4 + r;
                T[dcol * 136 + kvrow] = f2bf(aV[i][j][r] + bvv);
            }
        }
    }
    __syncthreads();
    {
        int d = tid >> 1, half = (tid & 1) * 64;
        US* vrow = VTout + ((size_t)(b_ * 8 + h) * 128 + d) * 4096 + tbase + half;
        const US* tr = &T[d * 136 + half];
#pragma unroll
        for (int s = 0; s < 8; ++s)
            *(us8*)(vrow + s * 8) = *(const us8*)(tr + s * 8);
    }
}

// ---------------- flash attention: S^T form, O^T output, split-KV, bitmask ----------------
// grid (4 qt of 128 q, 32 bh, 6 sp). 256 thr = 4 waves x 32 q-rows.
__global__ __launch_bounds__(256, 3)
void flash(const US* __restrict__ Qh, const US* __restrict__ Kh,
           const US* __restrict__ VTh, const unsigned long long* __restrict__ MBits,
           float* __restrict__ Opart, float* __restrict__ Lpart) {
    __shared__ US Ks[64 * 128];        // [kv][d] 16KB, swz (r&15)
    __shared__ US Vs[128 * 64];        // [d][kv] 16KB, swz (r&7)
    __shared__ US Ps[4][32 * 64];      // per-wave P [q][kv] 16KB, 16B-chunk swz (q&7)
    const int tid = threadIdx.x, wv = tid >> 6, ln = tid & 63;
    const int g = ln >> 4, c15 = ln & 15;
    const int qt = blockIdx.x, qbase = qt * 128;
    const int bh = blockIdx.y, b_ = bh >> 3;
    const int sp = blockIdx.z;
    const int t0 = (sp < 4) ? sp * 11 : 44 + (sp - 4) * 10;   // tiles of 64 kv
    const int nt = (sp < 4) ? 11 : 10;
    const int wq = wv * 32;

    // Q fragments (B-operand) straight from global
    bf16x8 qa[2][4];
#pragma unroll
    for (int ib = 0; ib < 2; ++ib) {
        const US* qrow = Qh + ((size_t)bh * 512 + qbase + wq + ib * 16 + c15) * 128;
#pragma unroll
        for (int ks = 0; ks < 4; ++ks)
            qa[ib][ks] = ldv8(qrow + ks * 32 + g * 8);
    }

    f32x4 o[8][2];
    const f32x4 z = {0.f, 0.f, 0.f, 0.f};
#pragma unroll
    for (int d = 0; d < 8; ++d) { o[d][0] = z; o[d][1] = z; }
    float l2[2] = {0.f, 0.f};

    const unsigned long long* Mrow[2];
    Mrow[0] = MBits + (size_t)(b_ * 512 + qbase + wq + c15) * 64;
    Mrow[1] = Mrow[0] + (size_t)16 * 64;
    const US* Kbase = Kh + ((size_t)bh * 4096 + (size_t)t0 * 64) * 128;
    const US* Vbase = VTh + (size_t)bh * 128 * 4096;
    US* Pw = &Ps[wv][0];

    for (int t = 0; t < nt; ++t) {
        int kv0 = (t0 + t) * 64;
        __syncthreads();
        const US* Kb = Kbase + (size_t)t * 64 * 128;
#pragma unroll
        for (int q = 0; q < 4; ++q) {               // K tile: rows kv, 128 d
            int eb = (q * 256 + wv * 64) * 8;
            int r = (eb >> 7) + (ln >> 4);
            int sw = (ln & 15) ^ (r & 15);
            gl_lds16(Kb + (size_t)r * 128 + sw * 8, &Ks[eb]);
        }
#pragma unroll
        for (int q = 0; q < 4; ++q) {               // V^T tile: rows d, 64 kv
            int eb = (q * 256 + wv * 64) * 8;
            int r = (eb >> 6) + (ln >> 3);
            int sw = (ln & 7) ^ (r & 7);
            gl_lds16(Vbase + (size_t)r * 4096 + kv0 + sw * 8, &Vs[eb]);
        }
        unsigned long long m64[2];
        m64[0] = Mrow[0][t0 + t];
        m64[1] = Mrow[1][t0 + t];
        __syncthreads();

        // S^T block-row per kb: 16 kv x 32 q, then exp/mask -> P LDS
#pragma unroll
        for (int kb = 0; kb < 4; ++kb) {
            f32x4 s0 = z, s1 = z;
#pragma unroll
            for (int ks = 0; ks < 4; ++ks) {
                bf16x8 kf = ldv8(&Ks[(kb * 16 + c15) * 128 + (((ks * 4 + g) ^ c15) * 8)]);
                s0 = __builtin_amdgcn_mfma_f32_16x16x32_bf16(kf, qa[0][ks], s0, 0, 0, 0);
                s1 = __builtin_amdgcn_mfma_f32_16x16x32_bf16(kf, qa[1][ks], s1, 0, 0, 0);
            }
            int cw = kb * 4 + g;
#pragma unroll
            for (int ib = 0; ib < 2; ++ib) {
                f32x4 sv = ib ? s1 : s0;
                unsigned mq = (unsigned)(m64[ib] >> (kb * 16 + g * 4)) & 15u;
                float p0 = (mq & 1u) ? __expf(sv[0]) : 0.f;
                float p1 = (mq & 2u) ? __expf(sv[1]) : 0.f;
                float p2 = (mq & 4u) ? __expf(sv[2]) : 0.f;
                float p3 = (mq & 8u) ? __expf(sv[3]) : 0.f;
                l2[ib] += (p0 + p1) + (p2 + p3);
                int q = ib * 16 + c15;
                US* wp = Pw + q * 64 + (((cw >> 1) ^ (q & 7)) * 8) + (cw & 1) * 4;
                us4 pv = { f2bf(p0), f2bf(p1), f2bf(p2), f2bf(p3) };
                *(us4*)wp = pv;
            }
        }

        // O^T += V^T P^T
#pragma unroll
        for (int ks = 0; ks < 2; ++ks) {
            bf16x8 pf[2];
#pragma unroll
            for (int ib = 0; ib < 2; ++ib) {
                int q = ib * 16 + c15;
                pf[ib] = ldv8(&Pw[q * 64 + (((ks * 4 + g) ^ (q & 7)) * 8)]);
            }
#pragma unroll
            for (int d = 0; d < 8; ++d) {
                bf16x8 vf = ldv8(&Vs[(d * 16 + c15) * 64 + (((ks * 4 + g) ^ (c15 & 7)) * 8)]);
                o[d][0] = __builtin_amdgcn_mfma_f32_16x16x32_bf16(vf, pf[0], o[d][0], 0, 0, 0);
                o[d][1] = __builtin_amdgcn_mfma_f32_16x16x32_bf16(vf, pf[1], o[d][1], 0, 0, 0);
            }
        }
    }

    // l: reduce over the 4 g-lanes sharing c15
    float lf[2];
#pragma unroll
    for (int ib = 0; ib < 2; ++ib) {
        float l = l2[ib];
        l += __shfl_xor(l, 16); l += __shfl_xor(l, 32);
        lf[ib] = l;
    }
    if (ln < 16) {
        size_t lb = ((size_t)sp * 32 + bh) * 512 + qbase + wq + c15;
        Lpart[lb] = lf[0];
        Lpart[lb + 16] = lf[1];
    }
    // Opart [sp][bh][d=128][q=512], un-normalized
    float* Ob = Opart + (((size_t)sp * 32 + bh) * 128 + g * 4) * 512 + qbase + wq + c15;
#pragma unroll
    for (int d = 0; d < 8; ++d)
#pragma unroll
        for (int r = 0; r < 4; ++r) {
            Ob[(size_t)(d * 16 + r) * 512] = o[d][0][r];
            Ob[(size_t)(d * 16 + r) * 512 + 16] = o[d][1][r];
        }
}

// ---------------- combine: sum 6 splits, normalize, transpose -> AO bf16 ----------------
__global__ void combine(const float* __restrict__ Opart, const float* __restrict__ Lpart,
                        US* __restrict__ AO) {
    __shared__ float linv[128];
    __shared__ float T[128 * 33];
    const int qt = blockIdx.x, bh = blockIdx.y;
    const int b_ = bh >> 3, h = bh & 7;
    const int tid = threadIdx.x;
    const size_t spstride = (size_t)32 * 128 * 512;

    if (tid < 128) {
        float s = 0.f;
#pragma unroll
        for (int sp = 0; sp < 6; ++sp)
            s += Lpart[((size_t)sp * 32 + bh) * 512 + qt * 128 + tid];
        linv[tid] = (s > 0.f) ? 1.f / s : 0.f;
    }
    __syncthreads();

    for (int ds0 = 0; ds0 < 128; ds0 += 32) {
        if (ds0) __syncthreads();
#pragma unroll
        for (int it = 0; it < 4; ++it) {
            int d = ds0 + (tid >> 5) + it * 8, qc = tid & 31;
            const float* base = Opart + ((size_t)bh * 128 + d) * 512 + qt * 128 + qc * 4;
            float4 a = {0.f, 0.f, 0.f, 0.f};
#pragma unroll
            for (int sp = 0; sp < 6; ++sp) {
                float4 v = *(const float4*)(base + sp * spstride);
                a.x += v.x; a.y += v.y; a.z += v.z; a.w += v.w;
            }
            int dd = d - ds0;
            T[(qc * 4 + 0) * 33 + dd] = a.x * linv[qc * 4 + 0];
            T[(qc * 4 + 1) * 33 + dd] = a.y * linv[qc * 4 + 1];
            T[(qc * 4 + 2) * 33 + dd] = a.z * linv[qc * 4 + 2];
            T[(qc * 4 + 3) * 33 + dd] = a.w * linv[qc * 4 + 3];
        }
        __syncthreads();
#pragma unroll
        for (int it = 0; it < 4; ++it) {
            int idx = tid + it * 256;
            int q = idx >> 3, c = idx & 7;
            const float* tr = &T[q * 33 + c * 4];
            us4 ov = { f2bf(tr[0]), f2bf(tr[1]), f2bf(tr[2]), f2bf(tr[3]) };
            *(us4*)(AO + ((size_t)(b_ * 512 + qt * 128 + q)) * 1024 + h * 128 + ds0 + c * 4) = ov;
        }
    }
}

// ---------------- launch ----------------
extern "C" void kernel_launch(void* const* d_in, const int* in_sizes, int n_in,
                              void* d_out, int out_size, void* d_ws, size_t ws_size,
                              hipStream_t stream) {
    (void)in_sizes; (void)n_in; (void)out_size; (void)ws_size;
    const float* Xq  = (const float*)d_in[0];
    const float* Xkv = (const float*)d_in[1];
    const int*   Mi  = (const int*)d_in[2];
    const float* Wq  = (const float*)d_in[3];
    const float* bq  = (const float*)d_in[4];
    const float* Wk  = (const float*)d_in[5];
    const float* bk  = (const float*)d_in[6];
    const float* Wv  = (const float*)d_in[7];
    const float* bv  = (const float*)d_in[8];
    const float* Wo  = (const float*)d_in[9];
    const float* bo  = (const float*)d_in[10];
    float* out = (float*)d_out;

    // ws layout (aliasing is stream-order safe):
    char* p = (char*)d_ws;
    US* WT   = (US*)p; p += (size_t)4 * 1024 * 1024 * 2;     // 8.4 MB, live to end
    US* AO   = (US*)p; p += (size_t)2048 * 1024 * 2;         // 4.2 MB
    US* XqB  = (US*)p; p += (size_t)2048 * 1024 * 2;         // 4.2 MB, dead after Q-proj
    US* Qh   = (US*)p; p += (size_t)2048 * 1024 * 2;         // 4.2 MB
    US* Kh   = (US*)p; p += (size_t)16384 * 1024 * 2;        // 33.5 MB
    US* VTh  = (US*)p; p += (size_t)16384 * 1024 * 2;        // 33.5 MB
    US* XkvB = (US*)p; p += (size_t)16384 * 1024 * 2;        // 33.5 MB, dead after gemm_kv
    char* OT = p;      p += (size_t)4 * 1024 * 1024 * 4;     // 16.8 MB Opart tail
    unsigned long long* MBits = (unsigned long long*)p; p += (size_t)131072 * 8;  // 1 MB
    (void)OT;
    float* Opart = (float*)XkvB;   // 50.3 MB = XkvB (33.5) + OT (16.8); XkvB dead by then
    float* Lpart = (float*)XqB;    // 393 KB; XqB dead after Q-proj

    prep<<<51200, 256, 0, stream>>>(Xq, Xkv, Mi, XqB, XkvB, MBits);
    wt_conv<<<dim3(32, 32, 4), 256, 0, stream>>>(Wq, Wk, Wv, Wo, WT);

    // Q projection: fold softmax scale 1/sqrt(128) into Q
    gemm_bt<0, 64><<<dim3(32, 8), 256, 0, stream>>>(XqB, WT, bq, Qh, 9, 0.08838834764831843f);
    gemm_kv<<<dim3(128, 8), 256, 0, stream>>>(XkvB, WT + 1048576, WT + 2097152,
                                              bk, bv, Kh, VTh);
    flash<<<dim3(4, 32, 6), 256, 0, stream>>>(Qh, Kh, VTh, MBits, Opart, Lpart);
    combine<<<dim3(4, 32), 256, 0, stream>>>(Opart, Lpart, AO);
    gemm_bt<1, 64><<<dim3(32, 8), 256, 0, stream>>>(AO, WT + 3145728, bo, out, 0, 1.0f);
}

// Round 5
// 344.054 us; speedup vs baseline: 1.4192x; 1.0229x over previous
//
#include <hip/hip_runtime.h>
#include <cstdint>
#include <cstddef>

typedef unsigned short US;
typedef __bf16 bf16_t;
typedef bf16_t bf16x8 __attribute__((ext_vector_type(8)));
typedef float  f32x4  __attribute__((ext_vector_type(4)));
typedef US     us8    __attribute__((ext_vector_type(8)));
typedef US     us4    __attribute__((ext_vector_type(4)));

#define AS1 __attribute__((address_space(1)))
#define AS3 __attribute__((address_space(3)))

__device__ __forceinline__ void gl_lds16(const void* g, void* l) {
    __builtin_amdgcn_global_load_lds((AS1 unsigned int*)(size_t)g,
                                     (AS3 unsigned int*)l, 16, 0, 0);
}

__device__ __forceinline__ US f2bf(float f) {
    unsigned u = __builtin_bit_cast(unsigned, f);
    u += 0x7FFFu + ((u >> 16) & 1u);   // RNE (inputs finite)
    return (US)(u >> 16);
}

__device__ __forceinline__ float bf2f(US u) {
    return __builtin_bit_cast(float, (unsigned)u << 16);
}

__device__ __forceinline__ bf16x8 ldv8(const US* p) {
    return __builtin_bit_cast(bf16x8, *(const us8*)p);
}

// ---------------- fused prep: converts + mask bits + weight transposes ----------------
__global__ void prep(const float* __restrict__ Xq, const float* __restrict__ Xkv,
                     const int* __restrict__ Mi, US* __restrict__ XqB,
                     US* __restrict__ XkvB, unsigned long long* __restrict__ MBits,
                     const float* __restrict__ Wq, const float* __restrict__ Wk,
                     const float* __restrict__ Wv, const float* __restrict__ Wo,
                     US* __restrict__ WTbase) {
    __shared__ float t[32][33];
    int b = blockIdx.x, tid = threadIdx.x;
    if (b < 2048) {
        int i = b * 256 + tid;
        float4 f = ((const float4*)Xq)[i];
        us4 o = { f2bf(f.x), f2bf(f.y), f2bf(f.z), f2bf(f.w) };
        ((us4*)XqB)[i] = o;
    } else if (b < 18432) {
        int i = (b - 2048) * 256 + tid;
        float4 f = ((const float4*)Xkv)[i];
        us4 o = { f2bf(f.x), f2bf(f.y), f2bf(f.z), f2bf(f.w) };
        ((us4*)XkvB)[i] = o;
    } else if (b < 51200) {
        int i = (b - 18432) * 256 + tid;   // one int/thread; wave = 64 consecutive kv
        int m = Mi[i];
        unsigned long long bits = __ballot(m != 0);
        if ((tid & 63) == 0) MBits[i >> 6] = bits;
    } else {
        int wb = b - 51200;                 // 4096 blocks: 4 weights x 32 x 32 tiles
        int z = wb >> 10, rr = wb & 1023;
        int bx = rr & 31, by = rr >> 5;
        const float* W = (z == 0) ? Wq : (z == 1) ? Wk : (z == 2) ? Wv : Wo;
        US* WT = WTbase + (size_t)z * 1024 * 1024;
        int tx = tid & 31, ty = tid >> 5;
        int x = bx * 32 + tx;
#pragma unroll
        for (int r = 0; r < 4; ++r)
            t[ty + r * 8][tx] = W[(size_t)(by * 32 + ty + r * 8) * 1024 + x];
        __syncthreads();
        int nx = by * 32 + tx;
#pragma unroll
        for (int r = 0; r < 4; ++r)
            WT[(size_t)(bx * 32 + ty + r * 8) * 1024 + nx] = f2bf(t[tx][ty + r * 8]);
    }
}

// ---------------- GEMM: C[M,1024] = A[M,1024]bf16 @ Bt[1024,1024]^T + bias ----------------
// BM = 128 (4x4 acc/wave) or 64 (2x4 acc/wave, doubles grid for small M).
// MODE 0: bf16 split-heads out; MODE 1: fp32 row-major [M,1024]
template <int MODE, int BM>
__global__ __launch_bounds__(256, 2)
void gemm_bt(const US* __restrict__ A, const US* __restrict__ Bt,
             const float* __restrict__ bias, void* __restrict__ out,
             int tlog2, float scale) {
    constexpr int K = 1024, N = 1024, BK = 64;
    constexpr int MI = BM / 32;                  // acc rows per wave
    __shared__ US As[BM * BK];
    __shared__ US Bs[128 * BK];
    const int tid = threadIdx.x;
    const int wv = tid >> 6, ln = tid & 63;
    const int g = ln >> 4, c15 = ln & 15;
    const int m0 = blockIdx.x * BM, n0 = blockIdx.y * 128;
    const int wm = (wv & 1) * (BM / 2), wn = (wv >> 1) * 64;

    f32x4 acc[MI][4];
    const f32x4 z = {0.f, 0.f, 0.f, 0.f};
#pragma unroll
    for (int i = 0; i < MI; ++i)
#pragma unroll
        for (int j = 0; j < 4; ++j) acc[i][j] = z;

    const US* Ab = A + (size_t)m0 * K;
    const US* Bb = Bt + (size_t)n0 * K;

    for (int k0 = 0; k0 < K; k0 += BK) {
        __syncthreads();
#pragma unroll
        for (int q = 0; q < BM / 32; ++q) {
            int eb = (q * 256 + wv * 64) * 8;
            int r = (eb >> 6) + (ln >> 3);
            int sw = (ln & 7) ^ (r & 7);
            gl_lds16(Ab + (size_t)r * K + k0 + sw * 8, &As[eb]);
        }
#pragma unroll
        for (int q = 0; q < 4; ++q) {
            int eb = (q * 256 + wv * 64) * 8;
            int r = (eb >> 6) + (ln >> 3);
            int sw = (ln & 7) ^ (r & 7);
            gl_lds16(Bb + (size_t)r * K + k0 + sw * 8, &Bs[eb]);
        }
        __syncthreads();
#pragma unroll
        for (int ks = 0; ks < 2; ++ks) {
            bf16x8 a[MI], b[4];
#pragma unroll
            for (int i = 0; i < MI; ++i) {
                int p = (ks * 4 + g) ^ (c15 & 7);
                a[i] = ldv8(&As[(wm + i * 16 + c15) * BK + p * 8]);
            }
#pragma unroll
            for (int j = 0; j < 4; ++j) {
                int p = (ks * 4 + g) ^ (c15 & 7);
                b[j] = ldv8(&Bs[(wn + j * 16 + c15) * BK + p * 8]);
            }
#pragma unroll
            for (int i = 0; i < MI; ++i)
#pragma unroll
                for (int j = 0; j < 4; ++j)
                    acc[i][j] = __builtin_amdgcn_mfma_f32_16x16x32_bf16(a[i], b[j], acc[i][j], 0, 0, 0);
        }
    }

#pragma unroll
    for (int i = 0; i < MI; ++i) {
#pragma unroll
        for (int j = 0; j < 4; ++j) {
            int col = n0 + wn + j * 16 + c15;
            float bvv = bias[col];
#pragma unroll
            for (int r = 0; r < 4; ++r) {
                int row = m0 + wm + i * 16 + g * 4 + r;
                float v = (acc[i][j][r] + bvv) * scale;
                if (MODE == 0) {
                    int b_ = row >> tlog2;
                    int t = row & ((1 << tlog2) - 1);
                    int h = col >> 7, d = col & 127;
                    ((US*)out)[(((size_t)(b_ * 8 + h) << tlog2) + t) * 128 + d] = f2bf(v);
                } else {
                    ((float*)out)[(size_t)row * N + col] = v;
                }
            }
        }
    }
}

// ---------------- fused K+V projection GEMM; V written pre-transposed ----------------
__global__ __launch_bounds__(256, 2)
void gemm_kv(const US* __restrict__ A, const US* __restrict__ BtK,
             const US* __restrict__ BtV, const float* __restrict__ bk,
             const float* __restrict__ bv, US* __restrict__ Kout,
             US* __restrict__ VTout) {
    constexpr int K = 1024, BK = 64;
    __shared__ US lds[3 * 128 * BK];           // As | BsK | BsV ; epilogue: T[128*136]
    US* As  = lds;
    US* BsK = lds + 128 * BK;
    US* BsV = lds + 2 * 128 * BK;
    const int tid = threadIdx.x;
    const int wv = tid >> 6, ln = tid & 63;
    const int g = ln >> 4, c15 = ln & 15;
    const int m0 = blockIdx.x * 128, n0 = blockIdx.y * 128;
    const int wm = (wv & 1) * 64, wn = (wv >> 1) * 64;

    f32x4 aK[4][4], aV[4][4];
    const f32x4 z = {0.f, 0.f, 0.f, 0.f};
#pragma unroll
    for (int i = 0; i < 4; ++i)
#pragma unroll
        for (int j = 0; j < 4; ++j) { aK[i][j] = z; aV[i][j] = z; }

    const US* Ab  = A   + (size_t)m0 * K;
    const US* BbK = BtK + (size_t)n0 * K;
    const US* BbV = BtV + (size_t)n0 * K;

    for (int k0 = 0; k0 < K; k0 += BK) {
        __syncthreads();
#pragma unroll
        for (int q = 0; q < 4; ++q) {
            int eb = (q * 256 + wv * 64) * 8;
            int r = (eb >> 6) + (ln >> 3);
            int sw = (ln & 7) ^ (r & 7);
            gl_lds16(Ab  + (size_t)r * K + k0 + sw * 8, &As[eb]);
            gl_lds16(BbK + (size_t)r * K + k0 + sw * 8, &BsK[eb]);
            gl_lds16(BbV + (size_t)r * K + k0 + sw * 8, &BsV[eb]);
        }
        __syncthreads();
#pragma unroll
        for (int ks = 0; ks < 2; ++ks) {
            bf16x8 a[4], bK[4], bV[4];
#pragma unroll
            for (int i = 0; i < 4; ++i) {
                int p = (ks * 4 + g) ^ (c15 & 7);
                a[i] = ldv8(&As[(wm + i * 16 + c15) * BK + p * 8]);
            }
#pragma unroll
            for (int j = 0; j < 4; ++j) {
                int p = (ks * 4 + g) ^ (c15 & 7);
                bK[j] = ldv8(&BsK[(wn + j * 16 + c15) * BK + p * 8]);
                bV[j] = ldv8(&BsV[(wn + j * 16 + c15) * BK + p * 8]);
            }
#pragma unroll
            for (int i = 0; i < 4; ++i)
#pragma unroll
                for (int j = 0; j < 4; ++j) {
                    aK[i][j] = __builtin_amdgcn_mfma_f32_16x16x32_bf16(a[i], bK[j], aK[i][j], 0, 0, 0);
                    aV[i][j] = __builtin_amdgcn_mfma_f32_16x16x32_bf16(a[i], bV[j], aV[i][j], 0, 0, 0);
                }
        }
    }

    const int h = n0 >> 7;
    const int b_ = m0 >> 12, tbase = m0 & 4095;

    // K epilogue: split-heads bf16 store
#pragma unroll
    for (int i = 0; i < 4; ++i) {
#pragma unroll
        for (int j = 0; j < 4; ++j) {
            int col = n0 + wn + j * 16 + c15;
            float bkv = bk[col];
            int d = col & 127;
#pragma unroll
            for (int r = 0; r < 4; ++r) {
                int row = m0 + wm + i * 16 + g * 4 + r;
                int t = row & 4095;
                Kout[(((size_t)(b_ * 8 + h) << 12) + t) * 128 + d] = f2bf(aK[i][j][r] + bkv);
            }
        }
    }

    // V epilogue: transpose tile through LDS, write VT rows (coalesced 256B)
    __syncthreads();
    US* T = lds;                                // [d 128][kv 128], stride 136
#pragma unroll
    for (int i = 0; i < 4; ++i) {
#pragma unroll
        for (int j = 0; j < 4; ++j) {
            int dcol = wn + j * 16 + c15;
            float bvv = bv[n0 + dcol];
#pragma unroll
            for (int r = 0; r < 4; ++r) {
                int kvrow = wm + i * 16 + g * 4 + r;
                T[dcol * 136 + kvrow] = f2bf(aV[i][j][r] + bvv);
            }
        }
    }
    __syncthreads();
    {
        int d = tid >> 1, half = (tid & 1) * 64;
        US* vrow = VTout + ((size_t)(b_ * 8 + h) * 128 + d) * 4096 + tbase + half;
        const US* tr = &T[d * 136 + half];
#pragma unroll
        for (int s = 0; s < 8; ++s)
            *(us8*)(vrow + s * 8) = *(const us8*)(tr + s * 8);
    }
}

// ---------------- flash attention: S^T form, O^T output, split-KV, bitmask ----------------
// 1-D grid of 768: id = qt*192 + bh*6 + sp  -> the 4 qt-siblings (sharing K/V) are
// congruent mod 8 => same XCD (L2 sharing). 256 thr = 4 waves x 32 q-rows.
__global__ __launch_bounds__(256, 3)
void flash(const US* __restrict__ Qh, const US* __restrict__ Kh,
           const US* __restrict__ VTh, const unsigned long long* __restrict__ MBits,
           US* __restrict__ Opart, float* __restrict__ Lpart) {
    __shared__ US Ks[64 * 128];        // [kv][d] 16KB, swz (r&15)
    __shared__ US Vs[128 * 64];        // [d][kv] 16KB, swz (r&7)
    __shared__ US Ps[4][32 * 64];      // per-wave P [q][kv] 16KB, 16B-chunk swz (q&7)
    const int tid = threadIdx.x, wv = tid >> 6, ln = tid & 63;
    const int g = ln >> 4, c15 = ln & 15;
    const int bid = blockIdx.x;
    const int qt = bid / 192;
    const int rest = bid - qt * 192;
    const int bh = rest / 6, sp = rest - bh * 6;
    const int qbase = qt * 128;
    const int b_ = bh >> 3;
    const int t0 = (sp < 4) ? sp * 11 : 44 + (sp - 4) * 10;   // tiles of 64 kv
    const int nt = (sp < 4) ? 11 : 10;
    const int wq = wv * 32;

    // Q fragments (B-operand) straight from global
    bf16x8 qa[2][4];
#pragma unroll
    for (int ib = 0; ib < 2; ++ib) {
        const US* qrow = Qh + ((size_t)bh * 512 + qbase + wq + ib * 16 + c15) * 128;
#pragma unroll
        for (int ks = 0; ks < 4; ++ks)
            qa[ib][ks] = ldv8(qrow + ks * 32 + g * 8);
    }

    f32x4 o[8][2];
    const f32x4 z = {0.f, 0.f, 0.f, 0.f};
#pragma unroll
    for (int d = 0; d < 8; ++d) { o[d][0] = z; o[d][1] = z; }
    float l2[2] = {0.f, 0.f};

    const unsigned long long* Mrow[2];
    Mrow[0] = MBits + (size_t)(b_ * 512 + qbase + wq + c15) * 64;
    Mrow[1] = Mrow[0] + (size_t)16 * 64;
    const US* Kbase = Kh + ((size_t)bh * 4096 + (size_t)t0 * 64) * 128;
    const US* Vbase = VTh + (size_t)bh * 128 * 4096;
    US* Pw = &Ps[wv][0];

    for (int t = 0; t < nt; ++t) {
        int kv0 = (t0 + t) * 64;
        __syncthreads();
        const US* Kb = Kbase + (size_t)t * 64 * 128;
#pragma unroll
        for (int q = 0; q < 4; ++q) {               // K tile: rows kv, 128 d
            int eb = (q * 256 + wv * 64) * 8;
            int r = (eb >> 7) + (ln >> 4);
            int sw = (ln & 15) ^ (r & 15);
            gl_lds16(Kb + (size_t)r * 128 + sw * 8, &Ks[eb]);
        }
#pragma unroll
        for (int q = 0; q < 4; ++q) {               // V^T tile: rows d, 64 kv
            int eb = (q * 256 + wv * 64) * 8;
            int r = (eb >> 6) + (ln >> 3);
            int sw = (ln & 7) ^ (r & 7);
            gl_lds16(Vbase + (size_t)r * 4096 + kv0 + sw * 8, &Vs[eb]);
        }
        unsigned long long m64[2];
        m64[0] = Mrow[0][t0 + t];
        m64[1] = Mrow[1][t0 + t];
        __syncthreads();

        // S^T block-row per kb: 16 kv x 32 q, then exp/mask -> P LDS
#pragma unroll
        for (int kb = 0; kb < 4; ++kb) {
            f32x4 s0 = z, s1 = z;
#pragma unroll
            for (int ks = 0; ks < 4; ++ks) {
                bf16x8 kf = ldv8(&Ks[(kb * 16 + c15) * 128 + (((ks * 4 + g) ^ c15) * 8)]);
                s0 = __builtin_amdgcn_mfma_f32_16x16x32_bf16(kf, qa[0][ks], s0, 0, 0, 0);
                s1 = __builtin_amdgcn_mfma_f32_16x16x32_bf16(kf, qa[1][ks], s1, 0, 0, 0);
            }
            int cw = kb * 4 + g;
#pragma unroll
            for (int ib = 0; ib < 2; ++ib) {
                f32x4 sv = ib ? s1 : s0;
                unsigned mq = (unsigned)(m64[ib] >> (kb * 16 + g * 4)) & 15u;
                float p0 = (mq & 1u) ? __expf(sv[0]) : 0.f;
                float p1 = (mq & 2u) ? __expf(sv[1]) : 0.f;
                float p2 = (mq & 4u) ? __expf(sv[2]) : 0.f;
                float p3 = (mq & 8u) ? __expf(sv[3]) : 0.f;
                l2[ib] += (p0 + p1) + (p2 + p3);
                int q = ib * 16 + c15;
                US* wp = Pw + q * 64 + (((cw >> 1) ^ (q & 7)) * 8) + (cw & 1) * 4;
                us4 pv = { f2bf(p0), f2bf(p1), f2bf(p2), f2bf(p3) };
                *(us4*)wp = pv;
            }
        }

        // O^T += V^T P^T
#pragma unroll
        for (int ks = 0; ks < 2; ++ks) {
            bf16x8 pf[2];
#pragma unroll
            for (int ib = 0; ib < 2; ++ib) {
                int q = ib * 16 + c15;
                pf[ib] = ldv8(&Pw[q * 64 + (((ks * 4 + g) ^ (q & 7)) * 8)]);
            }
#pragma unroll
            for (int d = 0; d < 8; ++d) {
                bf16x8 vf = ldv8(&Vs[(d * 16 + c15) * 64 + (((ks * 4 + g) ^ (c15 & 7)) * 8)]);
                o[d][0] = __builtin_amdgcn_mfma_f32_16x16x32_bf16(vf, pf[0], o[d][0], 0, 0, 0);
                o[d][1] = __builtin_amdgcn_mfma_f32_16x16x32_bf16(vf, pf[1], o[d][1], 0, 0, 0);
            }
        }
    }

    // l: reduce over the 4 g-lanes sharing c15
    float lf[2];
#pragma unroll
    for (int ib = 0; ib < 2; ++ib) {
        float l = l2[ib];
        l += __shfl_xor(l, 16); l += __shfl_xor(l, 32);
        lf[ib] = l;
    }
    if (ln < 16) {
        size_t lb = ((size_t)sp * 32 + bh) * 512 + qbase + wq + c15;
        Lpart[lb] = lf[0];
        Lpart[lb + 16] = lf[1];
    }
    // Opart [sp][bh][d=128][q=512], un-normalized bf16 partials
    US* Ob = Opart + (((size_t)sp * 32 + bh) * 128 + g * 4) * 512 + qbase + wq + c15;
#pragma unroll
    for (int d = 0; d < 8; ++d)
#pragma unroll
        for (int r = 0; r < 4; ++r) {
            Ob[(size_t)(d * 16 + r) * 512] = f2bf(o[d][0][r]);
            Ob[(size_t)(d * 16 + r) * 512 + 16] = f2bf(o[d][1][r]);
        }
}

// ---------------- combine: sum 6 bf16 splits, normalize, transpose -> AO bf16 ----------------
__global__ void combine(const US* __restrict__ Opart, const float* __restrict__ Lpart,
                        US* __restrict__ AO) {
    __shared__ float linv[128];
    __shared__ float T[128 * 33];
    const int qt = blockIdx.x, bh = blockIdx.y;
    const int b_ = bh >> 3, h = bh & 7;
    const int tid = threadIdx.x;
    const size_t spstride = (size_t)32 * 128 * 512;

    if (tid < 128) {
        float s = 0.f;
#pragma unroll
        for (int sp = 0; sp < 6; ++sp)
            s += Lpart[((size_t)sp * 32 + bh) * 512 + qt * 128 + tid];
        linv[tid] = (s > 0.f) ? 1.f / s : 0.f;
    }
    __syncthreads();

    for (int ds0 = 0; ds0 < 128; ds0 += 32) {
        if (ds0) __syncthreads();
        {
            int d = ds0 + (tid >> 3);          // 32 d-rows, 8 threads/row
            int q0 = (tid & 7) * 16;           // 16 q per thread
            const US* base = Opart + ((size_t)bh * 128 + d) * 512 + qt * 128 + q0;
            float acc[16];
#pragma unroll
            for (int i = 0; i < 16; ++i) acc[i] = 0.f;
#pragma unroll
            for (int sp = 0; sp < 6; ++sp) {
                us8 a = *(const us8*)(base + sp * spstride);
                us8 b = *(const us8*)(base + sp * spstride + 8);
#pragma unroll
                for (int i = 0; i < 8; ++i) {
                    acc[i] += bf2f(a[i]);
                    acc[8 + i] += bf2f(b[i]);
                }
            }
            int dd = d - ds0;
#pragma unroll
            for (int i = 0; i < 16; ++i)
                T[(q0 + i) * 33 + dd] = acc[i] * linv[q0 + i];
        }
        __syncthreads();
#pragma unroll
        for (int it = 0; it < 4; ++it) {
            int idx = tid + it * 256;
            int q = idx >> 3, c = idx & 7;
            const float* tr = &T[q * 33 + c * 4];
            us4 ov = { f2bf(tr[0]), f2bf(tr[1]), f2bf(tr[2]), f2bf(tr[3]) };
            *(us4*)(AO + ((size_t)(b_ * 512 + qt * 128 + q)) * 1024 + h * 128 + ds0 + c * 4) = ov;
        }
    }
}

// ---------------- launch ----------------
extern "C" void kernel_launch(void* const* d_in, const int* in_sizes, int n_in,
                              void* d_out, int out_size, void* d_ws, size_t ws_size,
                              hipStream_t stream) {
    (void)in_sizes; (void)n_in; (void)out_size; (void)ws_size;
    const float* Xq  = (const float*)d_in[0];
    const float* Xkv = (const float*)d_in[1];
    const int*   Mi  = (const int*)d_in[2];
    const float* Wq  = (const float*)d_in[3];
    const float* bq  = (const float*)d_in[4];
    const float* Wk  = (const float*)d_in[5];
    const float* bk  = (const float*)d_in[6];
    const float* Wv  = (const float*)d_in[7];
    const float* bv  = (const float*)d_in[8];
    const float* Wo  = (const float*)d_in[9];
    const float* bo  = (const float*)d_in[10];
    float* out = (float*)d_out;

    // ws layout (aliasing is stream-order safe):
    char* p = (char*)d_ws;
    US* WT   = (US*)p; p += (size_t)4 * 1024 * 1024 * 2;     // 8.4 MB, live to end
    US* AO   = (US*)p; p += (size_t)2048 * 1024 * 2;         // 4.2 MB
    US* XqB  = (US*)p; p += (size_t)2048 * 1024 * 2;         // 4.2 MB, dead after Q-proj
    US* Qh   = (US*)p; p += (size_t)2048 * 1024 * 2;         // 4.2 MB
    US* Kh   = (US*)p; p += (size_t)16384 * 1024 * 2;        // 33.5 MB
    US* VTh  = (US*)p; p += (size_t)16384 * 1024 * 2;        // 33.5 MB
    US* XkvB = (US*)p; p += (size_t)16384 * 1024 * 2;        // 33.5 MB, dead after gemm_kv
    unsigned long long* MBits = (unsigned long long*)p; p += (size_t)131072 * 8;  // 1 MB
    US* Opart    = XkvB;           // 25.2 MB bf16 partials inside XkvB (dead by flash)
    float* Lpart = (float*)XqB;    // 393 KB; XqB dead after Q-proj

    prep<<<55296, 256, 0, stream>>>(Xq, Xkv, Mi, XqB, XkvB, MBits, Wq, Wk, Wv, Wo, WT);

    // Q projection: fold softmax scale 1/sqrt(128) into Q
    gemm_bt<0, 64><<<dim3(32, 8), 256, 0, stream>>>(XqB, WT, bq, Qh, 9, 0.08838834764831843f);
    gemm_kv<<<dim3(128, 8), 256, 0, stream>>>(XkvB, WT + 1048576, WT + 2097152,
                                              bk, bv, Kh, VTh);
    flash<<<768, 256, 0, stream>>>(Qh, Kh, VTh, MBits, Opart, Lpart);
    combine<<<dim3(4, 32), 256, 0, stream>>>(Opart, Lpart, AO);
    gemm_bt<1, 64><<<dim3(32, 8), 256, 0, stream>>>(AO, WT + 3145728, bo, out, 0, 1.0f);
}